// Round 18
// baseline (971.117 us; speedup 1.0000x reference)
//
#include <hip/hip_runtime.h>
#include <stdint.h>

typedef uint32_t u32;
typedef _Float16 h2v __attribute__((ext_vector_type(2)));
typedef __attribute__((ext_vector_type(8))) short bf16x8;
typedef __attribute__((ext_vector_type(8))) _Float16 f16x8_t;
typedef __attribute__((ext_vector_type(4))) float f32x4;

#define NGRAPH 512

__device__ __forceinline__ float uif(u32 u) { return __builtin_bit_cast(float, u); }
__device__ __forceinline__ u32 fiu(float f) { return __builtin_bit_cast(u32, f); }
__device__ __forceinline__ unsigned short bf16r(float f) {
    return (unsigned short)((fiu(f) + 0x8000u) >> 16);
}
__device__ __forceinline__ u32 pack_bf16(float lo, float hi) {
    return ((fiu(lo) + 0x8000u) >> 16) | ((fiu(hi) + 0x8000u) & 0xFFFF0000u);
}
__device__ __forceinline__ u32 pkh(float a, float b) {
    unsigned short la = __builtin_bit_cast(unsigned short, (_Float16)a);
    unsigned short hb = __builtin_bit_cast(unsigned short, (_Float16)b);
    return (u32)la | ((u32)hb << 16);
}

// ---------------------------------------------------------------------------
// prep: BN folding (consts layout unchanged)
// ---------------------------------------------------------------------------
__global__ __launch_bounds__(256) void prep_kernel(
    const float* __restrict__ in_b, const float* __restrict__ in_g, const float* __restrict__ in_beta,
    const float* __restrict__ edge_b, const float* __restrict__ edge_g, const float* __restrict__ edge_beta,
    const float* __restrict__ bn_g, const float* __restrict__ bn_b,
    const float* __restrict__ out_b1, const float* __restrict__ out_g1, const float* __restrict__ out_beta1,
    float* __restrict__ consts)
{
    int c = threadIdx.x;
    if (c >= 128) return;
    const float rs = rsqrtf(1.0f + 1e-5f);
    float es = in_g[c] * rs;
    consts[c]       = es;
    consts[128 + c] = in_b[c] * es + in_beta[c];
    for (int l = 0; l < 4; ++l) {
        float s = edge_g[l*128 + c] * rs;
        consts[256  + l*128 + c] = s;
        consts[768  + l*128 + c] = edge_b[l*128 + c] * s + edge_beta[l*128 + c];
        float bs = bn_g[l*128 + c] * rs;
        consts[1280 + l*128 + c] = bs;
        consts[1792 + l*128 + c] = bn_b[l*128 + c];
    }
    float s1 = out_g1[c] * rs;
    consts[2304 + c] = s1;
    consts[2432 + c] = out_b1[c] * s1 + out_beta1[c];
}

// Pre-fragmented edge-MLP weights for mfma_f32_16x16x32_f16 (B operand),
// BN scale folded: W'[k][n] = W[k][n]*edge_g[n]*rs.  [R15/R16-verified layout]
__global__ __launch_bounds__(256) void wfrag_kernel(
    const float* __restrict__ edge_W, const float* __restrict__ edge_g,
    _Float16* __restrict__ wfrag)
{
    int idx = blockIdx.x*blockDim.x + threadIdx.x;
    if (idx >= 4*8*64*8) return;
    int j = idx & 7, lane = (idx >> 3) & 63, t = (idx >> 9) & 7, l = idx >> 12;
    int k = (lane >> 4)*8 + j;
    int n = t*16 + (lane & 15);
    const float rs = rsqrtf(1.0f + 1e-5f);
    wfrag[idx] = (k < 16)
        ? (_Float16)(edge_W[(l*16 + k)*128 + n] * (edge_g[l*128 + n] * rs))
        : (_Float16)0.f;
}

// Wt[w][n][k] = bf16(W[w][k][n]); w=0 encoder, w=1..4 conv layers
__global__ __launch_bounds__(256) void prepw_kernel(
    const float* __restrict__ in_W, const float* __restrict__ conv_W,
    unsigned short* __restrict__ WtAll)
{
    for (int idx = blockIdx.x*blockDim.x + threadIdx.x; idx < 5*128*128;
         idx += gridDim.x*blockDim.x) {
        int w = idx >> 14, rem = idx & 16383;
        int nn = rem >> 7, kk = rem & 127;
        const float* S = (w == 0) ? in_W : conv_W + (size_t)(w-1)*16384;
        WtAll[idx] = bf16r(S[kk*128 + nn]);
    }
}

// f32 x -> bf16 pairs
__global__ __launch_bounds__(256) void xconv_kernel(
    const float* __restrict__ x, u32* __restrict__ x16, int n4)
{
    for (int i = blockIdx.x*blockDim.x + threadIdx.x; i < n4;
         i += gridDim.x*blockDim.x) {
        float4 v = *(const float4*)(x + (size_t)i*4);
        uint2 o; o.x = pack_bf16(v.x, v.y); o.y = pack_bf16(v.z, v.w);
        *(uint2*)(x16 + (size_t)i*2) = o;
    }
}

__global__ __launch_bounds__(256) void count_kernel(
    const int* __restrict__ dst, int E, int* __restrict__ cnt)
{
    for (int e = blockIdx.x*blockDim.x + threadIdx.x; e < E; e += gridDim.x*blockDim.x)
        atomicAdd(&cnt[dst[e]], 1);
}

__global__ __launch_bounds__(1024) void scan_kernel(
    const int* __restrict__ cnt, int n, int E,
    int* __restrict__ offs, int* __restrict__ cursor)
{
    __shared__ int sh[1024];
    const int t = threadIdx.x;
    const int chunk = (n + 1023) >> 10;
    const int lo = t * chunk;
    const int hi = min(n, lo + chunk);
    int s = 0;
    for (int i = lo; i < hi; ++i) s += cnt[i];
    sh[t] = s;
    __syncthreads();
    for (int d = 1; d < 1024; d <<= 1) {
        int v = (t >= d) ? sh[t - d] : 0;
        __syncthreads();
        sh[t] += v;
        __syncthreads();
    }
    int base = sh[t] - s;
    for (int i = lo; i < hi; ++i) { int c = cnt[i]; offs[i] = base; cursor[i] = base; base += c; }
    if (t == 1023) offs[n] = E;
}

// ---------------------------------------------------------------------------
// Two-phase CSR build (R17 post-mortem: single-phase scatter was 145us at
// 1% VALUBusy with 153MB WRITE vs 58MB payload — random partial-line RMW).
// Phase 1: perm[p]=e only (4B random writes into a DENSE 6.4MB array —
//          every line eventually fully written, L2/L3 resident).
// Phase 2: sequential p: gather attr[perm[p]] (random reads; attr=102MB
//          fits L3 so each HBM line is fetched ~once), write attrp/srcoff
//          COALESCED.
// ---------------------------------------------------------------------------
__global__ __launch_bounds__(256) void scatter_perm_kernel(
    const int* __restrict__ dst, int E,
    int* __restrict__ cursor, int* __restrict__ perm)
{
    for (int e = blockIdx.x*blockDim.x + threadIdx.x; e < E; e += gridDim.x*blockDim.x) {
        int p = atomicAdd(&cursor[dst[e]], 1);
        perm[p] = e;
    }
}

__global__ __launch_bounds__(256) void apply_perm_kernel(
    const int* __restrict__ perm, const int* __restrict__ src,
    const float* __restrict__ attr, int E,
    int* __restrict__ srcoff, uint4* __restrict__ attrp)
{
    for (int p = blockIdx.x*blockDim.x + threadIdx.x; p < E; p += gridDim.x*blockDim.x) {
        const int e = perm[p];
        srcoff[p] = src[e] * 256;
        const float4* ar = (const float4*)(attr + (size_t)e*16);
        float4 v0 = ar[0], v1 = ar[1], v2 = ar[2], v3 = ar[3];
        uint4 o0, o1;
        o0.x = pkh(v0.x, v0.y); o0.y = pkh(v0.z, v0.w);
        o0.z = pkh(v1.x, v1.y); o0.w = pkh(v1.z, v1.w);
        o1.x = pkh(v2.x, v2.y); o1.y = pkh(v2.z, v2.w);
        o1.z = pkh(v3.x, v3.y); o1.w = pkh(v3.z, v3.w);
        attrp[2*(size_t)p] = o0; attrp[2*(size_t)p + 1] = o1;
    }
}

__global__ __launch_bounds__(256) void goff_kernel(
    const int* __restrict__ batch, int n, int* __restrict__ goff)
{
    int g = blockIdx.x*blockDim.x + threadIdx.x;
    if (g > NGRAPH) return;
    if (g == NGRAPH) { goff[NGRAPH] = n; return; }
    int lo = 0, hi = n;
    while (lo < hi) { int m = (lo + hi) >> 1; if (batch[m] < g) lo = m + 1; else hi = m; }
    goff[g] = lo;
}

// ---------------------------------------------------------------------------
// eagg2 (R17 verbatim): one pass computing eagg for layers (lbase, lbase+1)
// via MFMA; 16 B-frags AGPR-parked (free for MFMA), ~4 waves/SIMD occupancy.
// ---------------------------------------------------------------------------
__global__ __launch_bounds__(256) void eagg2_kernel(
    const uint4* __restrict__ attrp, const int* __restrict__ offs,
    const _Float16* __restrict__ wfrag, const float* __restrict__ consts,
    int lbase, u32* __restrict__ eagg, int n)
{
    __shared__ float eabuf[4][128];
    const int wave = threadIdx.x >> 6, lane = threadIdx.x & 63;
    const int c0 = lane * 2;
    const int l15 = lane & 15, l4 = lane >> 4;

    f16x8_t bw[16];
    #pragma unroll
    for (int lt = 0; lt < 16; ++lt)
        bw[lt] = *(const f16x8_t*)(wfrag + ((size_t)(lbase*8 + lt)*64 + lane)*8);
    float of[16];
    #pragma unroll
    for (int ll = 0; ll < 2; ++ll)
        #pragma unroll
        for (int t = 0; t < 8; ++t)
            of[ll*8 + t] = consts[768 + (lbase + ll)*128 + t*16 + l15];
    const f16x8_t az = (f16x8_t)(_Float16)0.f;

    for (int node = blockIdx.x*4 + wave; node < n; node += gridDim.x*4) {
        const int beg = offs[node], end = offs[node+1];
        float easum[16];
        #pragma unroll
        for (int lt = 0; lt < 16; ++lt) easum[lt] = 0.f;

        for (int g = beg; g < end; g += 16) {
            const int rem = end - g;
            f16x8_t a = az;
            if (l4 < 2) {
                int e = g + l15; if (e > end - 1) e = end - 1;  // clamp; masked below
                a = *(const f16x8_t*)((const char*)attrp + (size_t)e*32 + l4*16);
            }
            if (rem >= 16) {
                #pragma unroll
                for (int lt = 0; lt < 16; ++lt) {
                    f32x4 d = __builtin_amdgcn_mfma_f32_16x16x32_f16(
                        a, bw[lt], f32x4{0.f,0.f,0.f,0.f}, 0, 0, 0);
                    #pragma unroll
                    for (int r = 0; r < 4; ++r)
                        easum[lt] += fmaxf(d[r] + of[lt], 0.f);
                }
            } else {
                #pragma unroll
                for (int lt = 0; lt < 16; ++lt) {
                    f32x4 d = __builtin_amdgcn_mfma_f32_16x16x32_f16(
                        a, bw[lt], f32x4{0.f,0.f,0.f,0.f}, 0, 0, 0);
                    #pragma unroll
                    for (int r = 0; r < 4; ++r) {
                        float y = fmaxf(d[r] + of[lt], 0.f);
                        easum[lt] += ((l4*4 + r) < rem) ? y : 0.f;
                    }
                }
            }
        }
        #pragma unroll
        for (int ll = 0; ll < 2; ++ll) {
            #pragma unroll
            for (int t = 0; t < 8; ++t) {
                float v = easum[ll*8 + t];
                v += __shfl_xor(v, 16);
                v += __shfl_xor(v, 32);
                if (l4 == 0) eabuf[wave][t*16 + l15] = v;
            }
            float2 ea2 = *(float2*)&eabuf[wave][c0];
            eagg[(size_t)(lbase + ll)*n*64 + (size_t)node*64 + lane] =
                pack_bf16(ea2.x, ea2.y);
        }
    }
}

// ---------------------------------------------------------------------------
// hagg (R10 verbatim): Sum h[src] (relu(h+ea)=h+ea since h,ea>=0), 8-deep.
// Epilogue: C = (1+eps)*h[node] + hagg + eagg[l][node].
// ---------------------------------------------------------------------------
__global__ __launch_bounds__(256) void hagg_kernel(
    const char* __restrict__ hb, const int* __restrict__ srcoff,
    const int* __restrict__ offs, const u32* __restrict__ eagg_l,
    const float* __restrict__ epsp, int layer,
    u32* __restrict__ C16, int n)
{
    const int wave = threadIdx.x >> 6, lane = threadIdx.x & 63;
    const int lane4 = lane * 4;
    const float epsv = 1.0f + epsp[layer];
    for (int node = blockIdx.x*4 + wave; node < n; node += gridDim.x*4) {
        const int beg = offs[node], end = offs[node+1];
        float acc0 = 0.f, acc1 = 0.f;
        int i = beg;
        for (; i + 7 < end; i += 8) {
            const int iu = __builtin_amdgcn_readfirstlane(i);
            const int4 sa = *(const int4*)(srcoff + iu);
            const int4 sb = *(const int4*)(srcoff + iu + 4);
            const u32 h0 = *(const u32*)(hb + sa.x + lane4);
            const u32 h1 = *(const u32*)(hb + sa.y + lane4);
            const u32 h2 = *(const u32*)(hb + sa.z + lane4);
            const u32 h3 = *(const u32*)(hb + sa.w + lane4);
            const u32 h4 = *(const u32*)(hb + sb.x + lane4);
            const u32 h5 = *(const u32*)(hb + sb.y + lane4);
            const u32 h6 = *(const u32*)(hb + sb.z + lane4);
            const u32 h7 = *(const u32*)(hb + sb.w + lane4);
            acc0 += uif(h0 << 16); acc1 += uif(h0 & 0xFFFF0000u);
            acc0 += uif(h1 << 16); acc1 += uif(h1 & 0xFFFF0000u);
            acc0 += uif(h2 << 16); acc1 += uif(h2 & 0xFFFF0000u);
            acc0 += uif(h3 << 16); acc1 += uif(h3 & 0xFFFF0000u);
            acc0 += uif(h4 << 16); acc1 += uif(h4 & 0xFFFF0000u);
            acc0 += uif(h5 << 16); acc1 += uif(h5 & 0xFFFF0000u);
            acc0 += uif(h6 << 16); acc1 += uif(h6 & 0xFFFF0000u);
            acc0 += uif(h7 << 16); acc1 += uif(h7 & 0xFFFF0000u);
        }
        for (; i + 3 < end; i += 4) {
            const int iu = __builtin_amdgcn_readfirstlane(i);
            const int4 sa = *(const int4*)(srcoff + iu);
            const u32 h0 = *(const u32*)(hb + sa.x + lane4);
            const u32 h1 = *(const u32*)(hb + sa.y + lane4);
            const u32 h2 = *(const u32*)(hb + sa.z + lane4);
            const u32 h3 = *(const u32*)(hb + sa.w + lane4);
            acc0 += uif(h0 << 16); acc1 += uif(h0 & 0xFFFF0000u);
            acc0 += uif(h1 << 16); acc1 += uif(h1 & 0xFFFF0000u);
            acc0 += uif(h2 << 16); acc1 += uif(h2 & 0xFFFF0000u);
            acc0 += uif(h3 << 16); acc1 += uif(h3 & 0xFFFF0000u);
        }
        for (; i < end; ++i) {
            const int iu = __builtin_amdgcn_readfirstlane(i);
            const u32 h0 = *(const u32*)(hb + srcoff[iu] + lane4);
            acc0 += uif(h0 << 16); acc1 += uif(h0 & 0xFFFF0000u);
        }
        const u32 eg = eagg_l[(size_t)node*64 + lane];
        const u32 hn = *(const u32*)(hb + (size_t)node*256 + lane4);
        float t0 = fmaf(epsv, uif(hn << 16),          acc0 + uif(eg << 16));
        float t1 = fmaf(epsv, uif(hn & 0xFFFF0000u),  acc1 + uif(eg & 0xFFFF0000u));
        C16[(size_t)node*64 + lane] = pack_bf16(t0, t1);
    }
}

// ---------------------------------------------------------------------------
// bf16 MFMA GEMM (64 rows/block, R6 config), in-place safe.
// ---------------------------------------------------------------------------
__global__ __launch_bounds__(256) void conv_mfma_kernel(
    const unsigned short* X16, int M,
    const unsigned short* __restrict__ Wt,
    const float* __restrict__ scale, const float* __restrict__ off,
    const unsigned short* __restrict__ resid16,
    unsigned short* out16, int do_relu)
{
    __shared__ unsigned short Ws[128*128];
    for (int i = threadIdx.x*8; i < 128*128; i += 256*8) {
        int row = i >> 7;
        int bo = (i & 127) * 2;
        int4 v = *(const int4*)(Wt + i);
        *(int4*)((char*)Ws + row*256 + (bo ^ ((row & 7) << 4))) = v;
    }
    __syncthreads();
    const int wave = threadIdx.x >> 6, lane = threadIdx.x & 63;
    const int row0 = blockIdx.x*64 + wave*16;
    const int l15 = lane & 15, l4 = lane >> 4;
    int arow = row0 + l15; if (arow > M-1) arow = M-1;
    const unsigned short* ap = X16 + (size_t)arow*128 + l4*8;
    f32x4 acc[8];
    #pragma unroll
    for (int t = 0; t < 8; ++t) acc[t] = f32x4{0.f, 0.f, 0.f, 0.f};
    #pragma unroll
    for (int ks = 0; ks < 4; ++ks) {
        bf16x8 a = *(const bf16x8*)(ap + ks*32);
        #pragma unroll
        for (int t = 0; t < 8; ++t) {
            int brow = t*16 + l15;
            int bo = ks*64 + l4*16;
            bf16x8 b = *(const bf16x8*)((const char*)Ws + brow*256 + (bo ^ ((brow & 7) << 4)));
            acc[t] = __builtin_amdgcn_mfma_f32_16x16x32_bf16(a, b, acc[t], 0, 0, 0);
        }
    }
    #pragma unroll
    for (int t = 0; t < 8; ++t) {
        int col = t*16 + l15;
        float sc = scale[col], of = off[col];
        #pragma unroll
        for (int r = 0; r < 4; ++r) {
            int row = row0 + l4*4 + r;
            if (row < M) {
                float y = fmaf(acc[t][r], sc, of);
                if (do_relu) y = fmaxf(y, 0.f);
                if (resid16) y += uif((u32)resid16[(size_t)row*128 + col] << 16);
                out16[(size_t)row*128 + col] = bf16r(y);
            }
        }
    }
}

__global__ __launch_bounds__(256) void pool_kernel(
    const u32* __restrict__ h16, const int* __restrict__ goff,
    float* __restrict__ pooled)
{
    const int wave = threadIdx.x >> 6, lane = threadIdx.x & 63;
    const int g = blockIdx.x*4 + wave;
    if (g >= NGRAPH) return;
    float ax = 0.f, ay = 0.f;
    const int beg = goff[g], end = goff[g+1];
    for (int node = beg; node < end; ++node) {
        u32 v = h16[(size_t)node*64 + lane];
        ax += uif(v << 16); ay += uif(v & 0xFFFF0000u);
    }
    *(float2*)&pooled[g*128 + lane*2] = make_float2(ax, ay);
}

// fp32 vector GEMM for the small output MLP (512 rows)
__global__ __launch_bounds__(256) void gemm128_kernel(
    const float* __restrict__ in, int rows,
    const float* __restrict__ W,
    const float* __restrict__ scale, const float* __restrict__ off,
    float* out, int do_relu)
{
    __shared__ float Wsh[128*128];
    for (int i = threadIdx.x*4; i < 128*128; i += 256*4)
        *(float4*)&Wsh[i] = *(const float4*)&W[i];
    __syncthreads();
    const int wave = threadIdx.x >> 6, lane = threadIdx.x & 63;
    const int c0 = lane * 2;
    const float sc0 = scale ? scale[c0]   : 1.0f;
    const float sc1 = scale ? scale[c0+1] : 1.0f;
    const float of0 = off ? off[c0]   : 0.0f;
    const float of1 = off ? off[c0+1] : 0.0f;
    for (int rp = blockIdx.x*4 + wave; rp*2 < rows; rp += gridDim.x*4) {
        const int row0 = __builtin_amdgcn_readfirstlane(rp * 2);
        const float* xr = in + (size_t)row0 * 128;
        float a00 = 0.f, a01 = 0.f, a10 = 0.f, a11 = 0.f;
        #pragma unroll 8
        for (int k = 0; k < 128; ++k) {
            float x0 = xr[k];
            float x1 = xr[128 + k];
            float2 w = *(const float2*)&Wsh[k*128 + c0];
            a00 = fmaf(x0, w.x, a00); a01 = fmaf(x0, w.y, a01);
            a10 = fmaf(x1, w.x, a10); a11 = fmaf(x1, w.y, a11);
        }
        float y00 = fmaf(a00, sc0, of0), y01 = fmaf(a01, sc1, of1);
        float y10 = fmaf(a10, sc0, of0), y11 = fmaf(a11, sc1, of1);
        if (do_relu) {
            y00 = fmaxf(y00, 0.f); y01 = fmaxf(y01, 0.f);
            y10 = fmaxf(y10, 0.f); y11 = fmaxf(y11, 0.f);
        }
        *(float2*)&out[(size_t)row0*128 + c0]     = make_float2(y00, y01);
        *(float2*)&out[(size_t)(row0+1)*128 + c0] = make_float2(y10, y11);
    }
}

extern "C" void kernel_launch(void* const* d_in, const int* in_sizes, int n_in,
                              void* d_out, int out_size, void* d_ws, size_t ws_size,
                              hipStream_t stream)
{
    const float* x         = (const float*)d_in[0];
    const int*   eidx      = (const int*)d_in[1];
    const float* eattr     = (const float*)d_in[2];
    const int*   batch     = (const int*)d_in[3];
    const float* in_W      = (const float*)d_in[4];
    const float* in_b      = (const float*)d_in[5];
    const float* in_g      = (const float*)d_in[6];
    const float* in_beta   = (const float*)d_in[7];
    const float* edge_W    = (const float*)d_in[8];
    const float* edge_b    = (const float*)d_in[9];
    const float* edge_g    = (const float*)d_in[10];
    const float* edge_beta = (const float*)d_in[11];
    const float* conv_W    = (const float*)d_in[12];
    const float* epsp      = (const float*)d_in[13];
    const float* bn_g      = (const float*)d_in[14];
    const float* bn_b      = (const float*)d_in[15];
    const float* out_W1    = (const float*)d_in[16];
    const float* out_b1    = (const float*)d_in[17];
    const float* out_g1    = (const float*)d_in[18];
    const float* out_beta1 = (const float*)d_in[19];
    const float* out_W2    = (const float*)d_in[20];
    const float* out_b2    = (const float*)d_in[21];

    const int N = in_sizes[0] / 128;
    const int E = in_sizes[1] / 2;
    const int* src = eidx;
    const int* dst = eidx + E;

    char* ws = (char*)d_ws;
    size_t o = 0;
    auto alloc = [&](size_t bytes) { void* p = ws + o; o = (o + bytes + 255) & ~(size_t)255; return p; };
    unsigned short* P    = (unsigned short*)alloc((size_t)N * 128 * 2);
    unsigned short* Q    = (unsigned short*)alloc((size_t)N * 128 * 2);
    uint4* attrp         = (uint4*)alloc((size_t)E * 32);
    int*   srcoff        = (int*)alloc((size_t)E * 4);
    int*   perm          = (int*)alloc((size_t)E * 4);
    u32*   eagg          = (u32*)alloc((size_t)N * 64 * 4 * 4);  // 4 planes bf16x2
    int*   offs          = (int*)alloc((size_t)(N + 1) * 4);
    int*   cursor        = (int*)alloc((size_t)N * 4);
    int*   cnt           = (int*)alloc((size_t)N * 4);
    int*   goff          = (int*)alloc((NGRAPH + 1) * 4);
    float* pooled        = (float*)alloc(NGRAPH * 128 * 4);
    float* o1            = (float*)alloc(NGRAPH * 128 * 4);
    float* consts        = (float*)alloc(2560 * 4);
    _Float16* wfrag      = (_Float16*)alloc(4 * 8 * 64 * 8 * 2);
    unsigned short* WtAll = (unsigned short*)alloc(5 * 128 * 128 * 2);

    prep_kernel<<<1, 256, 0, stream>>>(in_b, in_g, in_beta,
                                       edge_b, edge_g, edge_beta,
                                       bn_g, bn_b, out_b1, out_g1, out_beta1,
                                       consts);
    wfrag_kernel<<<64, 256, 0, stream>>>(edge_W, edge_g, wfrag);
    prepw_kernel<<<80, 256, 0, stream>>>(in_W, conv_W, WtAll);
    xconv_kernel<<<2048, 256, 0, stream>>>(x, (u32*)Q, N * 32);

    (void)hipMemsetAsync(cnt, 0, (size_t)N * 4, stream);
    count_kernel<<<2048, 256, 0, stream>>>(dst, E, cnt);
    scan_kernel<<<1, 1024, 0, stream>>>(cnt, N, E, offs, cursor);
    scatter_perm_kernel<<<2048, 256, 0, stream>>>(dst, E, cursor, perm);
    apply_perm_kernel<<<2048, 256, 0, stream>>>(perm, src, eattr, E, srcoff, attrp);
    goff_kernel<<<3, 256, 0, stream>>>(batch, N, goff);

    const int gblocks = (N + 63) / 64;
    // input encoder, in-place on Q: h0 = bf16(relu(bn(x@in_W)))
    conv_mfma_kernel<<<gblocks, 256, 0, stream>>>(Q, N, WtAll,
                                                  consts, consts + 128,
                                                  nullptr, Q, 1);
    // edge aggregates: two 2-layer MFMA passes (occupancy-tuned, R16 lesson)
    eagg2_kernel<<<2048, 256, 0, stream>>>(attrp, offs, wfrag, consts, 0, eagg, N);
    eagg2_kernel<<<2048, 256, 0, stream>>>(attrp, offs, wfrag, consts, 2, eagg, N);

    unsigned short* cur = Q;
    unsigned short* oth = P;
    for (int l = 0; l < 4; ++l) {
        hagg_kernel<<<2048, 256, 0, stream>>>((const char*)cur, srcoff, offs,
                                              eagg + (size_t)l * N * 64,
                                              epsp, l, (u32*)oth, N);
        conv_mfma_kernel<<<gblocks, 256, 0, stream>>>(oth, N,
                                                      WtAll + (size_t)(1 + l)*16384,
                                                      consts + 1280 + l*128,
                                                      consts + 1792 + l*128,
                                                      cur, oth, 1);
        unsigned short* t = cur; cur = oth; oth = t;
    }

    pool_kernel<<<128, 256, 0, stream>>>((const u32*)cur, goff, pooled);

    gemm128_kernel<<<64, 256, 0, stream>>>(pooled, NGRAPH, out_W1,
                                           consts + 2304, consts + 2432, o1, 1);
    gemm128_kernel<<<64, 256, 0, stream>>>(o1, NGRAPH, out_W2,
                                           nullptr, out_b2, (float*)d_out, 0);
}

// Round 19
// 939.508 us; speedup vs baseline: 1.0336x; 1.0336x over previous
//
#include <hip/hip_runtime.h>
#include <stdint.h>

typedef uint32_t u32;
typedef _Float16 h2v __attribute__((ext_vector_type(2)));
typedef __attribute__((ext_vector_type(8))) short bf16x8;
typedef __attribute__((ext_vector_type(8))) _Float16 f16x8_t;
typedef __attribute__((ext_vector_type(4))) float f32x4;

#define NGRAPH 512
#define RSTRIDE 48   // fused edge record: attr 32B + srcoff 4B + 12B pad

__device__ __forceinline__ float uif(u32 u) { return __builtin_bit_cast(float, u); }
__device__ __forceinline__ u32 fiu(float f) { return __builtin_bit_cast(u32, f); }
__device__ __forceinline__ unsigned short bf16r(float f) {
    return (unsigned short)((fiu(f) + 0x8000u) >> 16);
}
__device__ __forceinline__ u32 pack_bf16(float lo, float hi) {
    return ((fiu(lo) + 0x8000u) >> 16) | ((fiu(hi) + 0x8000u) & 0xFFFF0000u);
}
__device__ __forceinline__ u32 pkh(float a, float b) {
    unsigned short la = __builtin_bit_cast(unsigned short, (_Float16)a);
    unsigned short hb = __builtin_bit_cast(unsigned short, (_Float16)b);
    return (u32)la | ((u32)hb << 16);
}

// ---------------------------------------------------------------------------
// prep: BN folding (consts layout unchanged)
// ---------------------------------------------------------------------------
__global__ __launch_bounds__(256) void prep_kernel(
    const float* __restrict__ in_b, const float* __restrict__ in_g, const float* __restrict__ in_beta,
    const float* __restrict__ edge_b, const float* __restrict__ edge_g, const float* __restrict__ edge_beta,
    const float* __restrict__ bn_g, const float* __restrict__ bn_b,
    const float* __restrict__ out_b1, const float* __restrict__ out_g1, const float* __restrict__ out_beta1,
    float* __restrict__ consts)
{
    int c = threadIdx.x;
    if (c >= 128) return;
    const float rs = rsqrtf(1.0f + 1e-5f);
    float es = in_g[c] * rs;
    consts[c]       = es;
    consts[128 + c] = in_b[c] * es + in_beta[c];
    for (int l = 0; l < 4; ++l) {
        float s = edge_g[l*128 + c] * rs;
        consts[256  + l*128 + c] = s;
        consts[768  + l*128 + c] = edge_b[l*128 + c] * s + edge_beta[l*128 + c];
        float bs = bn_g[l*128 + c] * rs;
        consts[1280 + l*128 + c] = bs;
        consts[1792 + l*128 + c] = bn_b[l*128 + c];
    }
    float s1 = out_g1[c] * rs;
    consts[2304 + c] = s1;
    consts[2432 + c] = out_b1[c] * s1 + out_beta1[c];
}

// Pre-fragmented edge-MLP weights for mfma_f32_16x16x32_f16 (B operand),
// BN scale folded: W'[k][n] = W[k][n]*edge_g[n]*rs; zero for k>=16 (K pad).
__global__ __launch_bounds__(256) void wfrag_kernel(
    const float* __restrict__ edge_W, const float* __restrict__ edge_g,
    _Float16* __restrict__ wfrag)
{
    int idx = blockIdx.x*blockDim.x + threadIdx.x;
    if (idx >= 4*8*64*8) return;
    int j = idx & 7, lane = (idx >> 3) & 63, t = (idx >> 9) & 7, l = idx >> 12;
    int k = (lane >> 4)*8 + j;
    int n = t*16 + (lane & 15);
    const float rs = rsqrtf(1.0f + 1e-5f);
    wfrag[idx] = (k < 16)
        ? (_Float16)(edge_W[(l*16 + k)*128 + n] * (edge_g[l*128 + n] * rs))
        : (_Float16)0.f;
}

// Wt[w][n][k] = bf16(W[w][k][n]); w=0 encoder, w=1..4 conv layers
__global__ __launch_bounds__(256) void prepw_kernel(
    const float* __restrict__ in_W, const float* __restrict__ conv_W,
    unsigned short* __restrict__ WtAll)
{
    for (int idx = blockIdx.x*blockDim.x + threadIdx.x; idx < 5*128*128;
         idx += gridDim.x*blockDim.x) {
        int w = idx >> 14, rem = idx & 16383;
        int nn = rem >> 7, kk = rem & 127;
        const float* S = (w == 0) ? in_W : conv_W + (size_t)(w-1)*16384;
        WtAll[idx] = bf16r(S[kk*128 + nn]);
    }
}

// f32 x -> bf16 pairs
__global__ __launch_bounds__(256) void xconv_kernel(
    const float* __restrict__ x, u32* __restrict__ x16, int n4)
{
    for (int i = blockIdx.x*blockDim.x + threadIdx.x; i < n4;
         i += gridDim.x*blockDim.x) {
        float4 v = *(const float4*)(x + (size_t)i*4);
        uint2 o; o.x = pack_bf16(v.x, v.y); o.y = pack_bf16(v.z, v.w);
        *(uint2*)(x16 + (size_t)i*2) = o;
    }
}

__global__ __launch_bounds__(256) void count_kernel(
    const int* __restrict__ dst, int E, int* __restrict__ cnt)
{
    for (int e = blockIdx.x*blockDim.x + threadIdx.x; e < E; e += gridDim.x*blockDim.x)
        atomicAdd(&cnt[dst[e]], 1);
}

__global__ __launch_bounds__(1024) void scan_kernel(
    const int* __restrict__ cnt, int n, int E,
    int* __restrict__ offs, int* __restrict__ cursor)
{
    __shared__ int sh[1024];
    const int t = threadIdx.x;
    const int chunk = (n + 1023) >> 10;
    const int lo = t * chunk;
    const int hi = min(n, lo + chunk);
    int s = 0;
    for (int i = lo; i < hi; ++i) s += cnt[i];
    sh[t] = s;
    __syncthreads();
    for (int d = 1; d < 1024; d <<= 1) {
        int v = (t >= d) ? sh[t - d] : 0;
        __syncthreads();
        sh[t] += v;
        __syncthreads();
    }
    int base = sh[t] - s;
    for (int i = lo; i < hi; ++i) { int c = cnt[i]; offs[i] = base; cursor[i] = base; base += c; }
    if (t == 1023) offs[n] = E;
}

// ---------------------------------------------------------------------------
// Single-phase CSR scatter into FUSED 48B records (R18 post-mortem: the cost
// is random write-LINE-TOUCHES, ~2/edge with split attrp+srcoff arrays; one
// contiguous 48B record per edge = ~1 touch). rec = [attr f16x16][srcoff][pad]
// Bytes >=32 of the A-fragment multiply ZERO weights (K padded 16->32), so
// the srcoff/pad bytes are numerically inert for eagg2.
// ---------------------------------------------------------------------------
__global__ __launch_bounds__(256) void scatter_kernel(
    const int* __restrict__ src, const int* __restrict__ dst,
    const float* __restrict__ attr, int E,
    int* __restrict__ cursor, char* __restrict__ rec)
{
    for (int e = blockIdx.x*blockDim.x + threadIdx.x; e < E; e += gridDim.x*blockDim.x) {
        int p = atomicAdd(&cursor[dst[e]], 1);
        const float4* ar = (const float4*)(attr + (size_t)e*16);
        float4 v0 = ar[0], v1 = ar[1], v2 = ar[2], v3 = ar[3];
        uint4 o0, o1;
        o0.x = pkh(v0.x, v0.y); o0.y = pkh(v0.z, v0.w);
        o0.z = pkh(v1.x, v1.y); o0.w = pkh(v1.z, v1.w);
        o1.x = pkh(v2.x, v2.y); o1.y = pkh(v2.z, v2.w);
        o1.z = pkh(v3.x, v3.y); o1.w = pkh(v3.z, v3.w);
        char* r = rec + (size_t)p * RSTRIDE;
        *(uint4*)(r)      = o0;
        *(uint4*)(r + 16) = o1;
        *(uint4*)(r + 32) = make_uint4((u32)(src[e] * 256), 0u, 0u, 0u);
    }
}

__global__ __launch_bounds__(256) void goff_kernel(
    const int* __restrict__ batch, int n, int* __restrict__ goff)
{
    int g = blockIdx.x*blockDim.x + threadIdx.x;
    if (g > NGRAPH) return;
    if (g == NGRAPH) { goff[NGRAPH] = n; return; }
    int lo = 0, hi = n;
    while (lo < hi) { int m = (lo + hi) >> 1; if (batch[m] < g) lo = m + 1; else hi = m; }
    goff[g] = lo;
}

// ---------------------------------------------------------------------------
// eagg2 (R17 structure): one pass computing eagg for layers (lbase, lbase+1)
// via MFMA; writes TWO PLANES (plane = layer-lbase; buffer reused mid-loop,
// R8 pattern, to keep ws under the proven budget).
// ---------------------------------------------------------------------------
__global__ __launch_bounds__(256) void eagg2_kernel(
    const char* __restrict__ rec, const int* __restrict__ offs,
    const _Float16* __restrict__ wfrag, const float* __restrict__ consts,
    int lbase, u32* __restrict__ eagg, int n)
{
    __shared__ float eabuf[4][128];
    const int wave = threadIdx.x >> 6, lane = threadIdx.x & 63;
    const int c0 = lane * 2;
    const int l15 = lane & 15, l4 = lane >> 4;

    f16x8_t bw[16];
    #pragma unroll
    for (int lt = 0; lt < 16; ++lt)
        bw[lt] = *(const f16x8_t*)(wfrag + ((size_t)(lbase*8 + lt)*64 + lane)*8);
    float of[16];
    #pragma unroll
    for (int ll = 0; ll < 2; ++ll)
        #pragma unroll
        for (int t = 0; t < 8; ++t)
            of[ll*8 + t] = consts[768 + (lbase + ll)*128 + t*16 + l15];
    const f16x8_t az = (f16x8_t)(_Float16)0.f;

    for (int node = blockIdx.x*4 + wave; node < n; node += gridDim.x*4) {
        const int beg = offs[node], end = offs[node+1];
        float easum[16];
        #pragma unroll
        for (int lt = 0; lt < 16; ++lt) easum[lt] = 0.f;

        for (int g = beg; g < end; g += 16) {
            const int rem = end - g;
            f16x8_t a = az;
            if (l4 < 2) {
                int e = g + l15; if (e > end - 1) e = end - 1;  // clamp; masked below
                a = *(const f16x8_t*)(rec + (size_t)e*RSTRIDE + l4*16);
            }
            if (rem >= 16) {
                #pragma unroll
                for (int lt = 0; lt < 16; ++lt) {
                    f32x4 d = __builtin_amdgcn_mfma_f32_16x16x32_f16(
                        a, bw[lt], f32x4{0.f,0.f,0.f,0.f}, 0, 0, 0);
                    #pragma unroll
                    for (int r = 0; r < 4; ++r)
                        easum[lt] += fmaxf(d[r] + of[lt], 0.f);
                }
            } else {
                #pragma unroll
                for (int lt = 0; lt < 16; ++lt) {
                    f32x4 d = __builtin_amdgcn_mfma_f32_16x16x32_f16(
                        a, bw[lt], f32x4{0.f,0.f,0.f,0.f}, 0, 0, 0);
                    #pragma unroll
                    for (int r = 0; r < 4; ++r) {
                        float y = fmaxf(d[r] + of[lt], 0.f);
                        easum[lt] += ((l4*4 + r) < rem) ? y : 0.f;
                    }
                }
            }
        }
        #pragma unroll
        for (int ll = 0; ll < 2; ++ll) {
            #pragma unroll
            for (int t = 0; t < 8; ++t) {
                float v = easum[ll*8 + t];
                v += __shfl_xor(v, 16);
                v += __shfl_xor(v, 32);
                if (l4 == 0) eabuf[wave][t*16 + l15] = v;
            }
            float2 ea2 = *(float2*)&eabuf[wave][c0];
            eagg[(size_t)ll*n*64 + (size_t)node*64 + lane] =
                pack_bf16(ea2.x, ea2.y);
        }
    }
}

// ---------------------------------------------------------------------------
// hagg: Sum h[src] (relu(h+ea)=h+ea since h,ea>=0), 8-deep; srcoff read from
// the fused record at +32 via wave-uniform scalar loads (imm offsets).
// Epilogue: C = (1+eps)*h[node] + hagg + eagg_plane[node].
// ---------------------------------------------------------------------------
__global__ __launch_bounds__(256) void hagg_kernel(
    const char* __restrict__ hb, const char* __restrict__ rec,
    const int* __restrict__ offs, const u32* __restrict__ eagg_l,
    const float* __restrict__ epsp, int layer,
    u32* __restrict__ C16, int n)
{
    const int wave = threadIdx.x >> 6, lane = threadIdx.x & 63;
    const int lane4 = lane * 4;
    const float epsv = 1.0f + epsp[layer];
    for (int node = blockIdx.x*4 + wave; node < n; node += gridDim.x*4) {
        const int beg = offs[node], end = offs[node+1];
        float acc0 = 0.f, acc1 = 0.f;
        int i = beg;
        for (; i + 7 < end; i += 8) {
            const int iu = __builtin_amdgcn_readfirstlane(i);
            const char* rb = rec + (size_t)iu*RSTRIDE + 32;
            const int so0 = *(const int*)(rb);
            const int so1 = *(const int*)(rb + RSTRIDE);
            const int so2 = *(const int*)(rb + 2*RSTRIDE);
            const int so3 = *(const int*)(rb + 3*RSTRIDE);
            const int so4 = *(const int*)(rb + 4*RSTRIDE);
            const int so5 = *(const int*)(rb + 5*RSTRIDE);
            const int so6 = *(const int*)(rb + 6*RSTRIDE);
            const int so7 = *(const int*)(rb + 7*RSTRIDE);
            const u32 h0 = *(const u32*)(hb + so0 + lane4);
            const u32 h1 = *(const u32*)(hb + so1 + lane4);
            const u32 h2 = *(const u32*)(hb + so2 + lane4);
            const u32 h3 = *(const u32*)(hb + so3 + lane4);
            const u32 h4 = *(const u32*)(hb + so4 + lane4);
            const u32 h5 = *(const u32*)(hb + so5 + lane4);
            const u32 h6 = *(const u32*)(hb + so6 + lane4);
            const u32 h7 = *(const u32*)(hb + so7 + lane4);
            acc0 += uif(h0 << 16); acc1 += uif(h0 & 0xFFFF0000u);
            acc0 += uif(h1 << 16); acc1 += uif(h1 & 0xFFFF0000u);
            acc0 += uif(h2 << 16); acc1 += uif(h2 & 0xFFFF0000u);
            acc0 += uif(h3 << 16); acc1 += uif(h3 & 0xFFFF0000u);
            acc0 += uif(h4 << 16); acc1 += uif(h4 & 0xFFFF0000u);
            acc0 += uif(h5 << 16); acc1 += uif(h5 & 0xFFFF0000u);
            acc0 += uif(h6 << 16); acc1 += uif(h6 & 0xFFFF0000u);
            acc0 += uif(h7 << 16); acc1 += uif(h7 & 0xFFFF0000u);
        }
        for (; i + 3 < end; i += 4) {
            const int iu = __builtin_amdgcn_readfirstlane(i);
            const char* rb = rec + (size_t)iu*RSTRIDE + 32;
            const int so0 = *(const int*)(rb);
            const int so1 = *(const int*)(rb + RSTRIDE);
            const int so2 = *(const int*)(rb + 2*RSTRIDE);
            const int so3 = *(const int*)(rb + 3*RSTRIDE);
            const u32 h0 = *(const u32*)(hb + so0 + lane4);
            const u32 h1 = *(const u32*)(hb + so1 + lane4);
            const u32 h2 = *(const u32*)(hb + so2 + lane4);
            const u32 h3 = *(const u32*)(hb + so3 + lane4);
            acc0 += uif(h0 << 16); acc1 += uif(h0 & 0xFFFF0000u);
            acc0 += uif(h1 << 16); acc1 += uif(h1 & 0xFFFF0000u);
            acc0 += uif(h2 << 16); acc1 += uif(h2 & 0xFFFF0000u);
            acc0 += uif(h3 << 16); acc1 += uif(h3 & 0xFFFF0000u);
        }
        for (; i < end; ++i) {
            const int iu = __builtin_amdgcn_readfirstlane(i);
            const int so0 = *(const int*)(rec + (size_t)iu*RSTRIDE + 32);
            const u32 h0 = *(const u32*)(hb + so0 + lane4);
            acc0 += uif(h0 << 16); acc1 += uif(h0 & 0xFFFF0000u);
        }
        const u32 eg = eagg_l[(size_t)node*64 + lane];
        const u32 hn = *(const u32*)(hb + (size_t)node*256 + lane4);
        float t0 = fmaf(epsv, uif(hn << 16),          acc0 + uif(eg << 16));
        float t1 = fmaf(epsv, uif(hn & 0xFFFF0000u),  acc1 + uif(eg & 0xFFFF0000u));
        C16[(size_t)node*64 + lane] = pack_bf16(t0, t1);
    }
}

// ---------------------------------------------------------------------------
// bf16 MFMA GEMM (64 rows/block, R6 config), in-place safe.
// ---------------------------------------------------------------------------
__global__ __launch_bounds__(256) void conv_mfma_kernel(
    const unsigned short* X16, int M,
    const unsigned short* __restrict__ Wt,
    const float* __restrict__ scale, const float* __restrict__ off,
    const unsigned short* __restrict__ resid16,
    unsigned short* out16, int do_relu)
{
    __shared__ unsigned short Ws[128*128];
    for (int i = threadIdx.x*8; i < 128*128; i += 256*8) {
        int row = i >> 7;
        int bo = (i & 127) * 2;
        int4 v = *(const int4*)(Wt + i);
        *(int4*)((char*)Ws + row*256 + (bo ^ ((row & 7) << 4))) = v;
    }
    __syncthreads();
    const int wave = threadIdx.x >> 6, lane = threadIdx.x & 63;
    const int row0 = blockIdx.x*64 + wave*16;
    const int l15 = lane & 15, l4 = lane >> 4;
    int arow = row0 + l15; if (arow > M-1) arow = M-1;
    const unsigned short* ap = X16 + (size_t)arow*128 + l4*8;
    f32x4 acc[8];
    #pragma unroll
    for (int t = 0; t < 8; ++t) acc[t] = f32x4{0.f, 0.f, 0.f, 0.f};
    #pragma unroll
    for (int ks = 0; ks < 4; ++ks) {
        bf16x8 a = *(const bf16x8*)(ap + ks*32);
        #pragma unroll
        for (int t = 0; t < 8; ++t) {
            int brow = t*16 + l15;
            int bo = ks*64 + l4*16;
            bf16x8 b = *(const bf16x8*)((const char*)Ws + brow*256 + (bo ^ ((brow & 7) << 4)));
            acc[t] = __builtin_amdgcn_mfma_f32_16x16x32_bf16(a, b, acc[t], 0, 0, 0);
        }
    }
    #pragma unroll
    for (int t = 0; t < 8; ++t) {
        int col = t*16 + l15;
        float sc = scale[col], of = off[col];
        #pragma unroll
        for (int r = 0; r < 4; ++r) {
            int row = row0 + l4*4 + r;
            if (row < M) {
                float y = fmaf(acc[t][r], sc, of);
                if (do_relu) y = fmaxf(y, 0.f);
                if (resid16) y += uif((u32)resid16[(size_t)row*128 + col] << 16);
                out16[(size_t)row*128 + col] = bf16r(y);
            }
        }
    }
}

__global__ __launch_bounds__(256) void pool_kernel(
    const u32* __restrict__ h16, const int* __restrict__ goff,
    float* __restrict__ pooled)
{
    const int wave = threadIdx.x >> 6, lane = threadIdx.x & 63;
    const int g = blockIdx.x*4 + wave;
    if (g >= NGRAPH) return;
    float ax = 0.f, ay = 0.f;
    const int beg = goff[g], end = goff[g+1];
    for (int node = beg; node < end; ++node) {
        u32 v = h16[(size_t)node*64 + lane];
        ax += uif(v << 16); ay += uif(v & 0xFFFF0000u);
    }
    *(float2*)&pooled[g*128 + lane*2] = make_float2(ax, ay);
}

// fp32 vector GEMM for the small output MLP (512 rows)
__global__ __launch_bounds__(256) void gemm128_kernel(
    const float* __restrict__ in, int rows,
    const float* __restrict__ W,
    const float* __restrict__ scale, const float* __restrict__ off,
    float* out, int do_relu)
{
    __shared__ float Wsh[128*128];
    for (int i = threadIdx.x*4; i < 128*128; i += 256*4)
        *(float4*)&Wsh[i] = *(const float4*)&W[i];
    __syncthreads();
    const int wave = threadIdx.x >> 6, lane = threadIdx.x & 63;
    const int c0 = lane * 2;
    const float sc0 = scale ? scale[c0]   : 1.0f;
    const float sc1 = scale ? scale[c0+1] : 1.0f;
    const float of0 = off ? off[c0]   : 0.0f;
    const float of1 = off ? off[c0+1] : 0.0f;
    for (int rp = blockIdx.x*4 + wave; rp*2 < rows; rp += gridDim.x*4) {
        const int row0 = __builtin_amdgcn_readfirstlane(rp * 2);
        const float* xr = in + (size_t)row0 * 128;
        float a00 = 0.f, a01 = 0.f, a10 = 0.f, a11 = 0.f;
        #pragma unroll 8
        for (int k = 0; k < 128; ++k) {
            float x0 = xr[k];
            float x1 = xr[128 + k];
            float2 w = *(const float2*)&Wsh[k*128 + c0];
            a00 = fmaf(x0, w.x, a00); a01 = fmaf(x0, w.y, a01);
            a10 = fmaf(x1, w.x, a10); a11 = fmaf(x1, w.y, a11);
        }
        float y00 = fmaf(a00, sc0, of0), y01 = fmaf(a01, sc1, of1);
        float y10 = fmaf(a10, sc0, of0), y11 = fmaf(a11, sc1, of1);
        if (do_relu) {
            y00 = fmaxf(y00, 0.f); y01 = fmaxf(y01, 0.f);
            y10 = fmaxf(y10, 0.f); y11 = fmaxf(y11, 0.f);
        }
        *(float2*)&out[(size_t)row0*128 + c0]     = make_float2(y00, y01);
        *(float2*)&out[(size_t)(row0+1)*128 + c0] = make_float2(y10, y11);
    }
}

extern "C" void kernel_launch(void* const* d_in, const int* in_sizes, int n_in,
                              void* d_out, int out_size, void* d_ws, size_t ws_size,
                              hipStream_t stream)
{
    const float* x         = (const float*)d_in[0];
    const int*   eidx      = (const int*)d_in[1];
    const float* eattr     = (const float*)d_in[2];
    const int*   batch     = (const int*)d_in[3];
    const float* in_W      = (const float*)d_in[4];
    const float* in_b      = (const float*)d_in[5];
    const float* in_g      = (const float*)d_in[6];
    const float* in_beta   = (const float*)d_in[7];
    const float* edge_W    = (const float*)d_in[8];
    const float* edge_b    = (const float*)d_in[9];
    const float* edge_g    = (const float*)d_in[10];
    const float* edge_beta = (const float*)d_in[11];
    const float* conv_W    = (const float*)d_in[12];
    const float* epsp      = (const float*)d_in[13];
    const float* bn_g      = (const float*)d_in[14];
    const float* bn_b      = (const float*)d_in[15];
    const float* out_W1    = (const float*)d_in[16];
    const float* out_b1    = (const float*)d_in[17];
    const float* out_g1    = (const float*)d_in[18];
    const float* out_beta1 = (const float*)d_in[19];
    const float* out_W2    = (const float*)d_in[20];
    const float* out_b2    = (const float*)d_in[21];

    const int N = in_sizes[0] / 128;
    const int E = in_sizes[1] / 2;
    const int* src = eidx;
    const int* dst = eidx + E;

    char* ws = (char*)d_ws;
    size_t o = 0;
    auto alloc = [&](size_t bytes) { void* p = ws + o; o = (o + bytes + 255) & ~(size_t)255; return p; };
    unsigned short* P    = (unsigned short*)alloc((size_t)N * 128 * 2);
    unsigned short* Q    = (unsigned short*)alloc((size_t)N * 128 * 2);
    char*  rec           = (char*)alloc((size_t)E * RSTRIDE);
    u32*   eagg          = (u32*)alloc((size_t)N * 64 * 2 * 4);  // 2 planes bf16x2
    int*   offs          = (int*)alloc((size_t)(N + 1) * 4);
    int*   cursor        = (int*)alloc((size_t)N * 4);
    int*   cnt           = (int*)alloc((size_t)N * 4);
    int*   goff          = (int*)alloc((NGRAPH + 1) * 4);
    float* pooled        = (float*)alloc(NGRAPH * 128 * 4);
    float* o1            = (float*)alloc(NGRAPH * 128 * 4);
    float* consts        = (float*)alloc(2560 * 4);
    _Float16* wfrag      = (_Float16*)alloc(4 * 8 * 64 * 8 * 2);
    unsigned short* WtAll = (unsigned short*)alloc(5 * 128 * 128 * 2);

    prep_kernel<<<1, 256, 0, stream>>>(in_b, in_g, in_beta,
                                       edge_b, edge_g, edge_beta,
                                       bn_g, bn_b, out_b1, out_g1, out_beta1,
                                       consts);
    wfrag_kernel<<<64, 256, 0, stream>>>(edge_W, edge_g, wfrag);
    prepw_kernel<<<80, 256, 0, stream>>>(in_W, conv_W, WtAll);
    xconv_kernel<<<2048, 256, 0, stream>>>(x, (u32*)Q, N * 32);

    (void)hipMemsetAsync(cnt, 0, (size_t)N * 4, stream);
    count_kernel<<<2048, 256, 0, stream>>>(dst, E, cnt);
    scan_kernel<<<1, 1024, 0, stream>>>(cnt, N, E, offs, cursor);
    scatter_kernel<<<2048, 256, 0, stream>>>(src, dst, eattr, E, cursor, rec);
    goff_kernel<<<3, 256, 0, stream>>>(batch, N, goff);

    const int gblocks = (N + 63) / 64;
    // input encoder, in-place on Q: h0 = bf16(relu(bn(x@in_W)))
    conv_mfma_kernel<<<gblocks, 256, 0, stream>>>(Q, N, WtAll,
                                                  consts, consts + 128,
                                                  nullptr, Q, 1);

    unsigned short* cur = Q;
    unsigned short* oth = P;
    for (int l = 0; l < 4; ++l) {
        if ((l & 1) == 0)  // 2-plane buffer: recompute for layer pair
            eagg2_kernel<<<2048, 256, 0, stream>>>(rec, offs, wfrag, consts,
                                                   l, eagg, N);
        hagg_kernel<<<2048, 256, 0, stream>>>((const char*)cur, rec, offs,
                                              eagg + (size_t)(l & 1) * N * 64,
                                              epsp, l, (u32*)oth, N);
        conv_mfma_kernel<<<gblocks, 256, 0, stream>>>(oth, N,
                                                      WtAll + (size_t)(1 + l)*16384,
                                                      consts + 1280 + l*128,
                                                      consts + 1792 + l*128,
                                                      cur, oth, 1);
        unsigned short* t = cur; cur = oth; oth = t;
    }

    pool_kernel<<<128, 256, 0, stream>>>((const u32*)cur, goff, pooled);

    gemm128_kernel<<<64, 256, 0, stream>>>(pooled, NGRAPH, out_W1,
                                           consts + 2304, consts + 2432, o1, 1);
    gemm128_kernel<<<64, 256, 0, stream>>>(o1, NGRAPH, out_W2,
                                           nullptr, out_b2, (float*)d_out, 0);
}

// Round 20
// 900.013 us; speedup vs baseline: 1.0790x; 1.0439x over previous
//
#include <hip/hip_runtime.h>
#include <stdint.h>

typedef uint32_t u32;
typedef _Float16 h2v __attribute__((ext_vector_type(2)));
typedef __attribute__((ext_vector_type(8))) short bf16x8;
typedef __attribute__((ext_vector_type(8))) _Float16 f16x8_t;
typedef __attribute__((ext_vector_type(4))) float f32x4;

#define NGRAPH 512
#define RSTRIDE 48   // fused edge record: attr 32B + srcoff 4B + 12B pad

__device__ __forceinline__ float uif(u32 u) { return __builtin_bit_cast(float, u); }
__device__ __forceinline__ u32 fiu(float f) { return __builtin_bit_cast(u32, f); }
__device__ __forceinline__ unsigned short bf16r(float f) {
    return (unsigned short)((fiu(f) + 0x8000u) >> 16);
}
__device__ __forceinline__ u32 pack_bf16(float lo, float hi) {
    return ((fiu(lo) + 0x8000u) >> 16) | ((fiu(hi) + 0x8000u) & 0xFFFF0000u);
}
__device__ __forceinline__ u32 pkh(float a, float b) {
    unsigned short la = __builtin_bit_cast(unsigned short, (_Float16)a);
    unsigned short hb = __builtin_bit_cast(unsigned short, (_Float16)b);
    return (u32)la | ((u32)hb << 16);
}

// ---------------------------------------------------------------------------
// prep: BN folding (consts layout unchanged)
// ---------------------------------------------------------------------------
__global__ __launch_bounds__(256) void prep_kernel(
    const float* __restrict__ in_b, const float* __restrict__ in_g, const float* __restrict__ in_beta,
    const float* __restrict__ edge_b, const float* __restrict__ edge_g, const float* __restrict__ edge_beta,
    const float* __restrict__ bn_g, const float* __restrict__ bn_b,
    const float* __restrict__ out_b1, const float* __restrict__ out_g1, const float* __restrict__ out_beta1,
    float* __restrict__ consts)
{
    int c = threadIdx.x;
    if (c >= 128) return;
    const float rs = rsqrtf(1.0f + 1e-5f);
    float es = in_g[c] * rs;
    consts[c]       = es;
    consts[128 + c] = in_b[c] * es + in_beta[c];
    for (int l = 0; l < 4; ++l) {
        float s = edge_g[l*128 + c] * rs;
        consts[256  + l*128 + c] = s;
        consts[768  + l*128 + c] = edge_b[l*128 + c] * s + edge_beta[l*128 + c];
        float bs = bn_g[l*128 + c] * rs;
        consts[1280 + l*128 + c] = bs;
        consts[1792 + l*128 + c] = bn_b[l*128 + c];
    }
    float s1 = out_g1[c] * rs;
    consts[2304 + c] = s1;
    consts[2432 + c] = out_b1[c] * s1 + out_beta1[c];
}

// Pre-fragmented edge-MLP weights for mfma_f32_16x16x32_f16 (B operand),
// BN scale folded: W'[k][n] = W[k][n]*edge_g[n]*rs; zero for k>=16 (K pad).
__global__ __launch_bounds__(256) void wfrag_kernel(
    const float* __restrict__ edge_W, const float* __restrict__ edge_g,
    _Float16* __restrict__ wfrag)
{
    int idx = blockIdx.x*blockDim.x + threadIdx.x;
    if (idx >= 4*8*64*8) return;
    int j = idx & 7, lane = (idx >> 3) & 63, t = (idx >> 9) & 7, l = idx >> 12;
    int k = (lane >> 4)*8 + j;
    int n = t*16 + (lane & 15);
    const float rs = rsqrtf(1.0f + 1e-5f);
    wfrag[idx] = (k < 16)
        ? (_Float16)(edge_W[(l*16 + k)*128 + n] * (edge_g[l*128 + n] * rs))
        : (_Float16)0.f;
}

// Wt[w][n][k] = bf16(W[w][k][n]); w=0 encoder, w=1..4 conv layers
__global__ __launch_bounds__(256) void prepw_kernel(
    const float* __restrict__ in_W, const float* __restrict__ conv_W,
    unsigned short* __restrict__ WtAll)
{
    for (int idx = blockIdx.x*blockDim.x + threadIdx.x; idx < 5*128*128;
         idx += gridDim.x*blockDim.x) {
        int w = idx >> 14, rem = idx & 16383;
        int nn = rem >> 7, kk = rem & 127;
        const float* S = (w == 0) ? in_W : conv_W + (size_t)(w-1)*16384;
        WtAll[idx] = bf16r(S[kk*128 + nn]);
    }
}

// f32 x -> bf16 pairs
__global__ __launch_bounds__(256) void xconv_kernel(
    const float* __restrict__ x, u32* __restrict__ x16, int n4)
{
    for (int i = blockIdx.x*blockDim.x + threadIdx.x; i < n4;
         i += gridDim.x*blockDim.x) {
        float4 v = *(const float4*)(x + (size_t)i*4);
        uint2 o; o.x = pack_bf16(v.x, v.y); o.y = pack_bf16(v.z, v.w);
        *(uint2*)(x16 + (size_t)i*2) = o;
    }
}

__global__ __launch_bounds__(256) void count_kernel(
    const int* __restrict__ dst, int E, int* __restrict__ cnt)
{
    for (int e = blockIdx.x*blockDim.x + threadIdx.x; e < E; e += gridDim.x*blockDim.x)
        atomicAdd(&cnt[dst[e]], 1);
}

__global__ __launch_bounds__(1024) void scan_kernel(
    const int* __restrict__ cnt, int n, int E,
    int* __restrict__ offs, int* __restrict__ cursor)
{
    __shared__ int sh[1024];
    const int t = threadIdx.x;
    const int chunk = (n + 1023) >> 10;
    const int lo = t * chunk;
    const int hi = min(n, lo + chunk);
    int s = 0;
    for (int i = lo; i < hi; ++i) s += cnt[i];
    sh[t] = s;
    __syncthreads();
    for (int d = 1; d < 1024; d <<= 1) {
        int v = (t >= d) ? sh[t - d] : 0;
        __syncthreads();
        sh[t] += v;
        __syncthreads();
    }
    int base = sh[t] - s;
    for (int i = lo; i < hi; ++i) { int c = cnt[i]; offs[i] = base; cursor[i] = base; base += c; }
    if (t == 1023) offs[n] = E;
}

// ---------------------------------------------------------------------------
// Single-phase CSR scatter into FUSED 48B records (R19-verified: ~1 random
// line-touch/edge — scatter dropped below the top-5).
// rec = [attr f16x16 (32B)][srcoff 4B][12B pad]; bytes >=32 multiply ZERO
// weights in eagg2 (K padded 16->32) so they are numerically inert.
// ---------------------------------------------------------------------------
__global__ __launch_bounds__(256) void scatter_kernel(
    const int* __restrict__ src, const int* __restrict__ dst,
    const float* __restrict__ attr, int E,
    int* __restrict__ cursor, char* __restrict__ rec)
{
    for (int e = blockIdx.x*blockDim.x + threadIdx.x; e < E; e += gridDim.x*blockDim.x) {
        int p = atomicAdd(&cursor[dst[e]], 1);
        const float4* ar = (const float4*)(attr + (size_t)e*16);
        float4 v0 = ar[0], v1 = ar[1], v2 = ar[2], v3 = ar[3];
        uint4 o0, o1;
        o0.x = pkh(v0.x, v0.y); o0.y = pkh(v0.z, v0.w);
        o0.z = pkh(v1.x, v1.y); o0.w = pkh(v1.z, v1.w);
        o1.x = pkh(v2.x, v2.y); o1.y = pkh(v2.z, v2.w);
        o1.z = pkh(v3.x, v3.y); o1.w = pkh(v3.z, v3.w);
        char* r = rec + (size_t)p * RSTRIDE;
        *(uint4*)(r)      = o0;
        *(uint4*)(r + 16) = o1;
        *(uint4*)(r + 32) = make_uint4((u32)(src[e] * 256), 0u, 0u, 0u);
    }
}

// Sequential extraction of the dense srcoff array from the fused records
// (R19 post-mortem: hagg's 48B-strided srcoff scalar loads cost ~15us/layer;
// this coalesced ~17us pass restores R17's dense-array hagg locality).
__global__ __launch_bounds__(256) void extract_srcoff_kernel(
    const char* __restrict__ rec, int E, int* __restrict__ srcoff)
{
    for (int p = blockIdx.x*blockDim.x + threadIdx.x; p < E; p += gridDim.x*blockDim.x)
        srcoff[p] = *(const int*)(rec + (size_t)p*RSTRIDE + 32);
}

__global__ __launch_bounds__(256) void goff_kernel(
    const int* __restrict__ batch, int n, int* __restrict__ goff)
{
    int g = blockIdx.x*blockDim.x + threadIdx.x;
    if (g > NGRAPH) return;
    if (g == NGRAPH) { goff[NGRAPH] = n; return; }
    int lo = 0, hi = n;
    while (lo < hi) { int m = (lo + hi) >> 1; if (batch[m] < g) lo = m + 1; else hi = m; }
    goff[g] = lo;
}

// ---------------------------------------------------------------------------
// eagg2 (R19 verbatim): one pass computing eagg for layers (lbase, lbase+1)
// via MFMA over the fused records; 2-plane output buffer (recomputed per
// layer pair).
// ---------------------------------------------------------------------------
__global__ __launch_bounds__(256) void eagg2_kernel(
    const char* __restrict__ rec, const int* __restrict__ offs,
    const _Float16* __restrict__ wfrag, const float* __restrict__ consts,
    int lbase, u32* __restrict__ eagg, int n)
{
    __shared__ float eabuf[4][128];
    const int wave = threadIdx.x >> 6, lane = threadIdx.x & 63;
    const int c0 = lane * 2;
    const int l15 = lane & 15, l4 = lane >> 4;

    f16x8_t bw[16];
    #pragma unroll
    for (int lt = 0; lt < 16; ++lt)
        bw[lt] = *(const f16x8_t*)(wfrag + ((size_t)(lbase*8 + lt)*64 + lane)*8);
    float of[16];
    #pragma unroll
    for (int ll = 0; ll < 2; ++ll)
        #pragma unroll
        for (int t = 0; t < 8; ++t)
            of[ll*8 + t] = consts[768 + (lbase + ll)*128 + t*16 + l15];
    const f16x8_t az = (f16x8_t)(_Float16)0.f;

    for (int node = blockIdx.x*4 + wave; node < n; node += gridDim.x*4) {
        const int beg = offs[node], end = offs[node+1];
        float easum[16];
        #pragma unroll
        for (int lt = 0; lt < 16; ++lt) easum[lt] = 0.f;

        for (int g = beg; g < end; g += 16) {
            const int rem = end - g;
            f16x8_t a = az;
            if (l4 < 2) {
                int e = g + l15; if (e > end - 1) e = end - 1;  // clamp; masked below
                a = *(const f16x8_t*)(rec + (size_t)e*RSTRIDE + l4*16);
            }
            if (rem >= 16) {
                #pragma unroll
                for (int lt = 0; lt < 16; ++lt) {
                    f32x4 d = __builtin_amdgcn_mfma_f32_16x16x32_f16(
                        a, bw[lt], f32x4{0.f,0.f,0.f,0.f}, 0, 0, 0);
                    #pragma unroll
                    for (int r = 0; r < 4; ++r)
                        easum[lt] += fmaxf(d[r] + of[lt], 0.f);
                }
            } else {
                #pragma unroll
                for (int lt = 0; lt < 16; ++lt) {
                    f32x4 d = __builtin_amdgcn_mfma_f32_16x16x32_f16(
                        a, bw[lt], f32x4{0.f,0.f,0.f,0.f}, 0, 0, 0);
                    #pragma unroll
                    for (int r = 0; r < 4; ++r) {
                        float y = fmaxf(d[r] + of[lt], 0.f);
                        easum[lt] += ((l4*4 + r) < rem) ? y : 0.f;
                    }
                }
            }
        }
        #pragma unroll
        for (int ll = 0; ll < 2; ++ll) {
            #pragma unroll
            for (int t = 0; t < 8; ++t) {
                float v = easum[ll*8 + t];
                v += __shfl_xor(v, 16);
                v += __shfl_xor(v, 32);
                if (l4 == 0) eabuf[wave][t*16 + l15] = v;
            }
            float2 ea2 = *(float2*)&eabuf[wave][c0];
            eagg[(size_t)ll*n*64 + (size_t)node*64 + lane] =
                pack_bf16(ea2.x, ea2.y);
        }
    }
}

// ---------------------------------------------------------------------------
// hagg (R17 verbatim, dense srcoff): Sum h[src] (relu(h+ea)=h+ea), 8-deep.
// Epilogue: C = (1+eps)*h[node] + hagg + eagg_plane[node].
// ---------------------------------------------------------------------------
__global__ __launch_bounds__(256) void hagg_kernel(
    const char* __restrict__ hb, const int* __restrict__ srcoff,
    const int* __restrict__ offs, const u32* __restrict__ eagg_l,
    const float* __restrict__ epsp, int layer,
    u32* __restrict__ C16, int n)
{
    const int wave = threadIdx.x >> 6, lane = threadIdx.x & 63;
    const int lane4 = lane * 4;
    const float epsv = 1.0f + epsp[layer];
    for (int node = blockIdx.x*4 + wave; node < n; node += gridDim.x*4) {
        const int beg = offs[node], end = offs[node+1];
        float acc0 = 0.f, acc1 = 0.f;
        int i = beg;
        for (; i + 7 < end; i += 8) {
            const int iu = __builtin_amdgcn_readfirstlane(i);
            const int4 sa = *(const int4*)(srcoff + iu);
            const int4 sb = *(const int4*)(srcoff + iu + 4);
            const u32 h0 = *(const u32*)(hb + sa.x + lane4);
            const u32 h1 = *(const u32*)(hb + sa.y + lane4);
            const u32 h2 = *(const u32*)(hb + sa.z + lane4);
            const u32 h3 = *(const u32*)(hb + sa.w + lane4);
            const u32 h4 = *(const u32*)(hb + sb.x + lane4);
            const u32 h5 = *(const u32*)(hb + sb.y + lane4);
            const u32 h6 = *(const u32*)(hb + sb.z + lane4);
            const u32 h7 = *(const u32*)(hb + sb.w + lane4);
            acc0 += uif(h0 << 16); acc1 += uif(h0 & 0xFFFF0000u);
            acc0 += uif(h1 << 16); acc1 += uif(h1 & 0xFFFF0000u);
            acc0 += uif(h2 << 16); acc1 += uif(h2 & 0xFFFF0000u);
            acc0 += uif(h3 << 16); acc1 += uif(h3 & 0xFFFF0000u);
            acc0 += uif(h4 << 16); acc1 += uif(h4 & 0xFFFF0000u);
            acc0 += uif(h5 << 16); acc1 += uif(h5 & 0xFFFF0000u);
            acc0 += uif(h6 << 16); acc1 += uif(h6 & 0xFFFF0000u);
            acc0 += uif(h7 << 16); acc1 += uif(h7 & 0xFFFF0000u);
        }
        for (; i + 3 < end; i += 4) {
            const int iu = __builtin_amdgcn_readfirstlane(i);
            const int4 sa = *(const int4*)(srcoff + iu);
            const u32 h0 = *(const u32*)(hb + sa.x + lane4);
            const u32 h1 = *(const u32*)(hb + sa.y + lane4);
            const u32 h2 = *(const u32*)(hb + sa.z + lane4);
            const u32 h3 = *(const u32*)(hb + sa.w + lane4);
            acc0 += uif(h0 << 16); acc1 += uif(h0 & 0xFFFF0000u);
            acc0 += uif(h1 << 16); acc1 += uif(h1 & 0xFFFF0000u);
            acc0 += uif(h2 << 16); acc1 += uif(h2 & 0xFFFF0000u);
            acc0 += uif(h3 << 16); acc1 += uif(h3 & 0xFFFF0000u);
        }
        for (; i < end; ++i) {
            const int iu = __builtin_amdgcn_readfirstlane(i);
            const u32 h0 = *(const u32*)(hb + srcoff[iu] + lane4);
            acc0 += uif(h0 << 16); acc1 += uif(h0 & 0xFFFF0000u);
        }
        const u32 eg = eagg_l[(size_t)node*64 + lane];
        const u32 hn = *(const u32*)(hb + (size_t)node*256 + lane4);
        float t0 = fmaf(epsv, uif(hn << 16),          acc0 + uif(eg << 16));
        float t1 = fmaf(epsv, uif(hn & 0xFFFF0000u),  acc1 + uif(eg & 0xFFFF0000u));
        C16[(size_t)node*64 + lane] = pack_bf16(t0, t1);
    }
}

// ---------------------------------------------------------------------------
// bf16 MFMA GEMM (64 rows/block, R6 config), in-place safe.
// ---------------------------------------------------------------------------
__global__ __launch_bounds__(256) void conv_mfma_kernel(
    const unsigned short* X16, int M,
    const unsigned short* __restrict__ Wt,
    const float* __restrict__ scale, const float* __restrict__ off,
    const unsigned short* __restrict__ resid16,
    unsigned short* out16, int do_relu)
{
    __shared__ unsigned short Ws[128*128];
    for (int i = threadIdx.x*8; i < 128*128; i += 256*8) {
        int row = i >> 7;
        int bo = (i & 127) * 2;
        int4 v = *(const int4*)(Wt + i);
        *(int4*)((char*)Ws + row*256 + (bo ^ ((row & 7) << 4))) = v;
    }
    __syncthreads();
    const int wave = threadIdx.x >> 6, lane = threadIdx.x & 63;
    const int row0 = blockIdx.x*64 + wave*16;
    const int l15 = lane & 15, l4 = lane >> 4;
    int arow = row0 + l15; if (arow > M-1) arow = M-1;
    const unsigned short* ap = X16 + (size_t)arow*128 + l4*8;
    f32x4 acc[8];
    #pragma unroll
    for (int t = 0; t < 8; ++t) acc[t] = f32x4{0.f, 0.f, 0.f, 0.f};
    #pragma unroll
    for (int ks = 0; ks < 4; ++ks) {
        bf16x8 a = *(const bf16x8*)(ap + ks*32);
        #pragma unroll
        for (int t = 0; t < 8; ++t) {
            int brow = t*16 + l15;
            int bo = ks*64 + l4*16;
            bf16x8 b = *(const bf16x8*)((const char*)Ws + brow*256 + (bo ^ ((brow & 7) << 4)));
            acc[t] = __builtin_amdgcn_mfma_f32_16x16x32_bf16(a, b, acc[t], 0, 0, 0);
        }
    }
    #pragma unroll
    for (int t = 0; t < 8; ++t) {
        int col = t*16 + l15;
        float sc = scale[col], of = off[col];
        #pragma unroll
        for (int r = 0; r < 4; ++r) {
            int row = row0 + l4*4 + r;
            if (row < M) {
                float y = fmaf(acc[t][r], sc, of);
                if (do_relu) y = fmaxf(y, 0.f);
                if (resid16) y += uif((u32)resid16[(size_t)row*128 + col] << 16);
                out16[(size_t)row*128 + col] = bf16r(y);
            }
        }
    }
}

__global__ __launch_bounds__(256) void pool_kernel(
    const u32* __restrict__ h16, const int* __restrict__ goff,
    float* __restrict__ pooled)
{
    const int wave = threadIdx.x >> 6, lane = threadIdx.x & 63;
    const int g = blockIdx.x*4 + wave;
    if (g >= NGRAPH) return;
    float ax = 0.f, ay = 0.f;
    const int beg = goff[g], end = goff[g+1];
    for (int node = beg; node < end; ++node) {
        u32 v = h16[(size_t)node*64 + lane];
        ax += uif(v << 16); ay += uif(v & 0xFFFF0000u);
    }
    *(float2*)&pooled[g*128 + lane*2] = make_float2(ax, ay);
}

// fp32 vector GEMM for the small output MLP (512 rows)
__global__ __launch_bounds__(256) void gemm128_kernel(
    const float* __restrict__ in, int rows,
    const float* __restrict__ W,
    const float* __restrict__ scale, const float* __restrict__ off,
    float* out, int do_relu)
{
    __shared__ float Wsh[128*128];
    for (int i = threadIdx.x*4; i < 128*128; i += 256*4)
        *(float4*)&Wsh[i] = *(const float4*)&W[i];
    __syncthreads();
    const int wave = threadIdx.x >> 6, lane = threadIdx.x & 63;
    const int c0 = lane * 2;
    const float sc0 = scale ? scale[c0]   : 1.0f;
    const float sc1 = scale ? scale[c0+1] : 1.0f;
    const float of0 = off ? off[c0]   : 0.0f;
    const float of1 = off ? off[c0+1] : 0.0f;
    for (int rp = blockIdx.x*4 + wave; rp*2 < rows; rp += gridDim.x*4) {
        const int row0 = __builtin_amdgcn_readfirstlane(rp * 2);
        const float* xr = in + (size_t)row0 * 128;
        float a00 = 0.f, a01 = 0.f, a10 = 0.f, a11 = 0.f;
        #pragma unroll 8
        for (int k = 0; k < 128; ++k) {
            float x0 = xr[k];
            float x1 = xr[128 + k];
            float2 w = *(const float2*)&Wsh[k*128 + c0];
            a00 = fmaf(x0, w.x, a00); a01 = fmaf(x0, w.y, a01);
            a10 = fmaf(x1, w.x, a10); a11 = fmaf(x1, w.y, a11);
        }
        float y00 = fmaf(a00, sc0, of0), y01 = fmaf(a01, sc1, of1);
        float y10 = fmaf(a10, sc0, of0), y11 = fmaf(a11, sc1, of1);
        if (do_relu) {
            y00 = fmaxf(y00, 0.f); y01 = fmaxf(y01, 0.f);
            y10 = fmaxf(y10, 0.f); y11 = fmaxf(y11, 0.f);
        }
        *(float2*)&out[(size_t)row0*128 + c0]     = make_float2(y00, y01);
        *(float2*)&out[(size_t)(row0+1)*128 + c0] = make_float2(y10, y11);
    }
}

extern "C" void kernel_launch(void* const* d_in, const int* in_sizes, int n_in,
                              void* d_out, int out_size, void* d_ws, size_t ws_size,
                              hipStream_t stream)
{
    const float* x         = (const float*)d_in[0];
    const int*   eidx      = (const int*)d_in[1];
    const float* eattr     = (const float*)d_in[2];
    const int*   batch     = (const int*)d_in[3];
    const float* in_W      = (const float*)d_in[4];
    const float* in_b      = (const float*)d_in[5];
    const float* in_g      = (const float*)d_in[6];
    const float* in_beta   = (const float*)d_in[7];
    const float* edge_W    = (const float*)d_in[8];
    const float* edge_b    = (const float*)d_in[9];
    const float* edge_g    = (const float*)d_in[10];
    const float* edge_beta = (const float*)d_in[11];
    const float* conv_W    = (const float*)d_in[12];
    const float* epsp      = (const float*)d_in[13];
    const float* bn_g      = (const float*)d_in[14];
    const float* bn_b      = (const float*)d_in[15];
    const float* out_W1    = (const float*)d_in[16];
    const float* out_b1    = (const float*)d_in[17];
    const float* out_g1    = (const float*)d_in[18];
    const float* out_beta1 = (const float*)d_in[19];
    const float* out_W2    = (const float*)d_in[20];
    const float* out_b2    = (const float*)d_in[21];

    const int N = in_sizes[0] / 128;
    const int E = in_sizes[1] / 2;
    const int* src = eidx;
    const int* dst = eidx + E;

    char* ws = (char*)d_ws;
    size_t o = 0;
    auto alloc = [&](size_t bytes) { void* p = ws + o; o = (o + bytes + 255) & ~(size_t)255; return p; };
    unsigned short* P    = (unsigned short*)alloc((size_t)N * 128 * 2);
    unsigned short* Q    = (unsigned short*)alloc((size_t)N * 128 * 2);
    char*  rec           = (char*)alloc((size_t)E * RSTRIDE);
    int*   srcoff        = (int*)alloc((size_t)E * 4);
    u32*   eagg          = (u32*)alloc((size_t)N * 64 * 2 * 4);  // 2 planes bf16x2
    int*   offs          = (int*)alloc((size_t)(N + 1) * 4);
    int*   cursor        = (int*)alloc((size_t)N * 4);
    int*   cnt           = (int*)alloc((size_t)N * 4);
    int*   goff          = (int*)alloc((NGRAPH + 1) * 4);
    float* pooled        = (float*)alloc(NGRAPH * 128 * 4);
    float* o1            = (float*)alloc(NGRAPH * 128 * 4);
    float* consts        = (float*)alloc(2560 * 4);
    _Float16* wfrag      = (_Float16*)alloc(4 * 8 * 64 * 8 * 2);
    unsigned short* WtAll = (unsigned short*)alloc(5 * 128 * 128 * 2);

    prep_kernel<<<1, 256, 0, stream>>>(in_b, in_g, in_beta,
                                       edge_b, edge_g, edge_beta,
                                       bn_g, bn_b, out_b1, out_g1, out_beta1,
                                       consts);
    wfrag_kernel<<<64, 256, 0, stream>>>(edge_W, edge_g, wfrag);
    prepw_kernel<<<80, 256, 0, stream>>>(in_W, conv_W, WtAll);
    xconv_kernel<<<2048, 256, 0, stream>>>(x, (u32*)Q, N * 32);

    (void)hipMemsetAsync(cnt, 0, (size_t)N * 4, stream);
    count_kernel<<<2048, 256, 0, stream>>>(dst, E, cnt);
    scan_kernel<<<1, 1024, 0, stream>>>(cnt, N, E, offs, cursor);
    scatter_kernel<<<2048, 256, 0, stream>>>(src, dst, eattr, E, cursor, rec);
    extract_srcoff_kernel<<<2048, 256, 0, stream>>>(rec, E, srcoff);
    goff_kernel<<<3, 256, 0, stream>>>(batch, N, goff);

    const int gblocks = (N + 63) / 64;
    // input encoder, in-place on Q: h0 = bf16(relu(bn(x@in_W)))
    conv_mfma_kernel<<<gblocks, 256, 0, stream>>>(Q, N, WtAll,
                                                  consts, consts + 128,
                                                  nullptr, Q, 1);

    unsigned short* cur = Q;
    unsigned short* oth = P;
    for (int l = 0; l < 4; ++l) {
        if ((l & 1) == 0)  // 2-plane buffer: recompute per layer pair
            eagg2_kernel<<<2048, 256, 0, stream>>>(rec, offs, wfrag, consts,
                                                   l, eagg, N);
        hagg_kernel<<<2048, 256, 0, stream>>>((const char*)cur, srcoff, offs,
                                              eagg + (size_t)(l & 1) * N * 64,
                                              epsp, l, (u32*)oth, N);
        conv_mfma_kernel<<<gblocks, 256, 0, stream>>>(oth, N,
                                                      WtAll + (size_t)(1 + l)*16384,
                                                      consts + 1280 + l*128,
                                                      consts + 1792 + l*128,
                                                      cur, oth, 1);
        unsigned short* t = cur; cur = oth; oth = t;
    }

    pool_kernel<<<128, 256, 0, stream>>>((const u32*)cur, goff, pooled);

    gemm128_kernel<<<64, 256, 0, stream>>>(pooled, NGRAPH, out_W1,
                                           consts + 2304, consts + 2432, o1, 1);
    gemm128_kernel<<<64, 256, 0, stream>>>(o1, NGRAPH, out_W2,
                                           nullptr, out_b2, (float*)d_out, 0);
}

// Round 21
// 886.019 us; speedup vs baseline: 1.0960x; 1.0158x over previous
//
#include <hip/hip_runtime.h>
#include <stdint.h>

typedef uint32_t u32;
typedef _Float16 h2v __attribute__((ext_vector_type(2)));
typedef __attribute__((ext_vector_type(8))) short bf16x8;
typedef __attribute__((ext_vector_type(8))) _Float16 f16x8_t;
typedef __attribute__((ext_vector_type(4))) float f32x4;

#define NGRAPH 512
#define RSTRIDE 48   // fused edge record: attr 32B + srcoff 4B + 12B pad

__device__ __forceinline__ float uif(u32 u) { return __builtin_bit_cast(float, u); }
__device__ __forceinline__ u32 fiu(float f) { return __builtin_bit_cast(u32, f); }
__device__ __forceinline__ unsigned short bf16r(float f) {
    return (unsigned short)((fiu(f) + 0x8000u) >> 16);
}
__device__ __forceinline__ u32 pack_bf16(float lo, float hi) {
    return ((fiu(lo) + 0x8000u) >> 16) | ((fiu(hi) + 0x8000u) & 0xFFFF0000u);
}
__device__ __forceinline__ u32 pkh(float a, float b) {
    unsigned short la = __builtin_bit_cast(unsigned short, (_Float16)a);
    unsigned short hb = __builtin_bit_cast(unsigned short, (_Float16)b);
    return (u32)la | ((u32)hb << 16);
}

// ---------------------------------------------------------------------------
// prep: BN folding (consts layout unchanged)
// ---------------------------------------------------------------------------
__global__ __launch_bounds__(256) void prep_kernel(
    const float* __restrict__ in_b, const float* __restrict__ in_g, const float* __restrict__ in_beta,
    const float* __restrict__ edge_b, const float* __restrict__ edge_g, const float* __restrict__ edge_beta,
    const float* __restrict__ bn_g, const float* __restrict__ bn_b,
    const float* __restrict__ out_b1, const float* __restrict__ out_g1, const float* __restrict__ out_beta1,
    float* __restrict__ consts)
{
    int c = threadIdx.x;
    if (c >= 128) return;
    const float rs = rsqrtf(1.0f + 1e-5f);
    float es = in_g[c] * rs;
    consts[c]       = es;
    consts[128 + c] = in_b[c] * es + in_beta[c];
    for (int l = 0; l < 4; ++l) {
        float s = edge_g[l*128 + c] * rs;
        consts[256  + l*128 + c] = s;
        consts[768  + l*128 + c] = edge_b[l*128 + c] * s + edge_beta[l*128 + c];
        float bs = bn_g[l*128 + c] * rs;
        consts[1280 + l*128 + c] = bs;
        consts[1792 + l*128 + c] = bn_b[l*128 + c];
    }
    float s1 = out_g1[c] * rs;
    consts[2304 + c] = s1;
    consts[2432 + c] = out_b1[c] * s1 + out_beta1[c];
}

// Pre-fragmented edge-MLP weights for mfma_f32_16x16x32_f16 (B operand),
// BN scale folded: W'[k][n] = W[k][n]*edge_g[n]*rs; zero for k>=16 (K pad).
__global__ __launch_bounds__(256) void wfrag_kernel(
    const float* __restrict__ edge_W, const float* __restrict__ edge_g,
    _Float16* __restrict__ wfrag)
{
    int idx = blockIdx.x*blockDim.x + threadIdx.x;
    if (idx >= 4*8*64*8) return;
    int j = idx & 7, lane = (idx >> 3) & 63, t = (idx >> 9) & 7, l = idx >> 12;
    int k = (lane >> 4)*8 + j;
    int n = t*16 + (lane & 15);
    const float rs = rsqrtf(1.0f + 1e-5f);
    wfrag[idx] = (k < 16)
        ? (_Float16)(edge_W[(l*16 + k)*128 + n] * (edge_g[l*128 + n] * rs))
        : (_Float16)0.f;
}

// Wt[w][n][k] = bf16(W[w][k][n]); w=0 encoder, w=1..4 conv layers
__global__ __launch_bounds__(256) void prepw_kernel(
    const float* __restrict__ in_W, const float* __restrict__ conv_W,
    unsigned short* __restrict__ WtAll)
{
    for (int idx = blockIdx.x*blockDim.x + threadIdx.x; idx < 5*128*128;
         idx += gridDim.x*blockDim.x) {
        int w = idx >> 14, rem = idx & 16383;
        int nn = rem >> 7, kk = rem & 127;
        const float* S = (w == 0) ? in_W : conv_W + (size_t)(w-1)*16384;
        WtAll[idx] = bf16r(S[kk*128 + nn]);
    }
}

// f32 x -> bf16 pairs
__global__ __launch_bounds__(256) void xconv_kernel(
    const float* __restrict__ x, u32* __restrict__ x16, int n4)
{
    for (int i = blockIdx.x*blockDim.x + threadIdx.x; i < n4;
         i += gridDim.x*blockDim.x) {
        float4 v = *(const float4*)(x + (size_t)i*4);
        uint2 o; o.x = pack_bf16(v.x, v.y); o.y = pack_bf16(v.z, v.w);
        *(uint2*)(x16 + (size_t)i*2) = o;
    }
}

__global__ __launch_bounds__(256) void count_kernel(
    const int* __restrict__ dst, int E, int* __restrict__ cnt)
{
    for (int e = blockIdx.x*blockDim.x + threadIdx.x; e < E; e += gridDim.x*blockDim.x)
        atomicAdd(&cnt[dst[e]], 1);
}

__global__ __launch_bounds__(1024) void scan_kernel(
    const int* __restrict__ cnt, int n, int E,
    int* __restrict__ offs, int* __restrict__ cursor)
{
    __shared__ int sh[1024];
    const int t = threadIdx.x;
    const int chunk = (n + 1023) >> 10;
    const int lo = t * chunk;
    const int hi = min(n, lo + chunk);
    int s = 0;
    for (int i = lo; i < hi; ++i) s += cnt[i];
    sh[t] = s;
    __syncthreads();
    for (int d = 1; d < 1024; d <<= 1) {
        int v = (t >= d) ? sh[t - d] : 0;
        __syncthreads();
        sh[t] += v;
        __syncthreads();
    }
    int base = sh[t] - s;
    for (int i = lo; i < hi; ++i) { int c = cnt[i]; offs[i] = base; cursor[i] = base; base += c; }
    if (t == 1023) offs[n] = E;
}

// ---------------------------------------------------------------------------
// Single-phase CSR scatter into FUSED 48B records (R19-verified: ~1 random
// line-touch/edge). rec = [attr f16x16 (32B)][srcoff 4B][12B pad]; bytes
// >=32 multiply ZERO weights in eagg2 (K padded 16->32) — numerically inert.
// ---------------------------------------------------------------------------
__global__ __launch_bounds__(256) void scatter_kernel(
    const int* __restrict__ src, const int* __restrict__ dst,
    const float* __restrict__ attr, int E,
    int* __restrict__ cursor, char* __restrict__ rec)
{
    for (int e = blockIdx.x*blockDim.x + threadIdx.x; e < E; e += gridDim.x*blockDim.x) {
        int p = atomicAdd(&cursor[dst[e]], 1);
        const float4* ar = (const float4*)(attr + (size_t)e*16);
        float4 v0 = ar[0], v1 = ar[1], v2 = ar[2], v3 = ar[3];
        uint4 o0, o1;
        o0.x = pkh(v0.x, v0.y); o0.y = pkh(v0.z, v0.w);
        o0.z = pkh(v1.x, v1.y); o0.w = pkh(v1.z, v1.w);
        o1.x = pkh(v2.x, v2.y); o1.y = pkh(v2.z, v2.w);
        o1.z = pkh(v3.x, v3.y); o1.w = pkh(v3.z, v3.w);
        char* r = rec + (size_t)p * RSTRIDE;
        *(uint4*)(r)      = o0;
        *(uint4*)(r + 16) = o1;
        *(uint4*)(r + 32) = make_uint4((u32)(src[e] * 256), 0u, 0u, 0u);
    }
}

// Sequential extraction of the dense srcoff array (R20-verified: restores
// hagg's dense-array locality for ~17us).
__global__ __launch_bounds__(256) void extract_srcoff_kernel(
    const char* __restrict__ rec, int E, int* __restrict__ srcoff)
{
    for (int p = blockIdx.x*blockDim.x + threadIdx.x; p < E; p += gridDim.x*blockDim.x)
        srcoff[p] = *(const int*)(rec + (size_t)p*RSTRIDE + 32);
}

__global__ __launch_bounds__(256) void goff_kernel(
    const int* __restrict__ batch, int n, int* __restrict__ goff)
{
    int g = blockIdx.x*blockDim.x + threadIdx.x;
    if (g > NGRAPH) return;
    if (g == NGRAPH) { goff[NGRAPH] = n; return; }
    int lo = 0, hi = n;
    while (lo < hi) { int m = (lo + hi) >> 1; if (batch[m] < g) lo = m + 1; else hi = m; }
    goff[g] = lo;
}

// ---------------------------------------------------------------------------
// eagg2: one pass computing eagg for layers (lbase, lbase+1) via MFMA.
// R21: 32-edge main groups — TWO A-fragments loaded up-front per iteration,
// two independent MFMA chains per weight-frag (R20 post-mortem: the 16-edge
// loop was ILP-bound — every group's 16 MFMAs + epilogue hung off one
// fragment load at ~2.5 waves/SIMD occupancy). Tail: 16-group + masked.
// ---------------------------------------------------------------------------
__global__ __launch_bounds__(256) void eagg2_kernel(
    const char* __restrict__ rec, const int* __restrict__ offs,
    const _Float16* __restrict__ wfrag, const float* __restrict__ consts,
    int lbase, u32* __restrict__ eagg, int n)
{
    __shared__ float eabuf[4][128];
    const int wave = threadIdx.x >> 6, lane = threadIdx.x & 63;
    const int c0 = lane * 2;
    const int l15 = lane & 15, l4 = lane >> 4;

    f16x8_t bw[16];
    #pragma unroll
    for (int lt = 0; lt < 16; ++lt)
        bw[lt] = *(const f16x8_t*)(wfrag + ((size_t)(lbase*8 + lt)*64 + lane)*8);
    float of[16];
    #pragma unroll
    for (int ll = 0; ll < 2; ++ll)
        #pragma unroll
        for (int t = 0; t < 8; ++t)
            of[ll*8 + t] = consts[768 + (lbase + ll)*128 + t*16 + l15];
    const f16x8_t az = (f16x8_t)(_Float16)0.f;

    for (int node = blockIdx.x*4 + wave; node < n; node += gridDim.x*4) {
        const int beg = offs[node], end = offs[node+1];
        float easum[16];
        #pragma unroll
        for (int lt = 0; lt < 16; ++lt) easum[lt] = 0.f;

        int g = beg;
        // 32-edge main loop: two independent fragments in flight
        for (; g + 32 <= end; g += 32) {
            f16x8_t a0 = az, a1 = az;
            if (l4 < 2) {
                a0 = *(const f16x8_t*)(rec + (size_t)(g + l15)*RSTRIDE + l4*16);
                a1 = *(const f16x8_t*)(rec + (size_t)(g + 16 + l15)*RSTRIDE + l4*16);
            }
            #pragma unroll
            for (int lt = 0; lt < 16; ++lt) {
                f32x4 d0 = __builtin_amdgcn_mfma_f32_16x16x32_f16(
                    a0, bw[lt], f32x4{0.f,0.f,0.f,0.f}, 0, 0, 0);
                f32x4 d1 = __builtin_amdgcn_mfma_f32_16x16x32_f16(
                    a1, bw[lt], f32x4{0.f,0.f,0.f,0.f}, 0, 0, 0);
                #pragma unroll
                for (int r = 0; r < 4; ++r)
                    easum[lt] += fmaxf(d0[r] + of[lt], 0.f);
                #pragma unroll
                for (int r = 0; r < 4; ++r)
                    easum[lt] += fmaxf(d1[r] + of[lt], 0.f);
            }
        }
        // 16-edge / masked tail (R19-verified path)
        for (; g < end; g += 16) {
            const int rem = end - g;
            f16x8_t a = az;
            if (l4 < 2) {
                int e = g + l15; if (e > end - 1) e = end - 1;  // clamp; masked below
                a = *(const f16x8_t*)(rec + (size_t)e*RSTRIDE + l4*16);
            }
            if (rem >= 16) {
                #pragma unroll
                for (int lt = 0; lt < 16; ++lt) {
                    f32x4 d = __builtin_amdgcn_mfma_f32_16x16x32_f16(
                        a, bw[lt], f32x4{0.f,0.f,0.f,0.f}, 0, 0, 0);
                    #pragma unroll
                    for (int r = 0; r < 4; ++r)
                        easum[lt] += fmaxf(d[r] + of[lt], 0.f);
                }
            } else {
                #pragma unroll
                for (int lt = 0; lt < 16; ++lt) {
                    f32x4 d = __builtin_amdgcn_mfma_f32_16x16x32_f16(
                        a, bw[lt], f32x4{0.f,0.f,0.f,0.f}, 0, 0, 0);
                    #pragma unroll
                    for (int r = 0; r < 4; ++r) {
                        float y = fmaxf(d[r] + of[lt], 0.f);
                        easum[lt] += ((l4*4 + r) < rem) ? y : 0.f;
                    }
                }
            }
        }
        #pragma unroll
        for (int ll = 0; ll < 2; ++ll) {
            #pragma unroll
            for (int t = 0; t < 8; ++t) {
                float v = easum[ll*8 + t];
                v += __shfl_xor(v, 16);
                v += __shfl_xor(v, 32);
                if (l4 == 0) eabuf[wave][t*16 + l15] = v;
            }
            float2 ea2 = *(float2*)&eabuf[wave][c0];
            eagg[(size_t)ll*n*64 + (size_t)node*64 + lane] =
                pack_bf16(ea2.x, ea2.y);
        }
    }
}

// ---------------------------------------------------------------------------
// hagg (R17 verbatim, dense srcoff): Sum h[src] (relu(h+ea)=h+ea), 8-deep.
// Epilogue: C = (1+eps)*h[node] + hagg + eagg_plane[node].
// ---------------------------------------------------------------------------
__global__ __launch_bounds__(256) void hagg_kernel(
    const char* __restrict__ hb, const int* __restrict__ srcoff,
    const int* __restrict__ offs, const u32* __restrict__ eagg_l,
    const float* __restrict__ epsp, int layer,
    u32* __restrict__ C16, int n)
{
    const int wave = threadIdx.x >> 6, lane = threadIdx.x & 63;
    const int lane4 = lane * 4;
    const float epsv = 1.0f + epsp[layer];
    for (int node = blockIdx.x*4 + wave; node < n; node += gridDim.x*4) {
        const int beg = offs[node], end = offs[node+1];
        float acc0 = 0.f, acc1 = 0.f;
        int i = beg;
        for (; i + 7 < end; i += 8) {
            const int iu = __builtin_amdgcn_readfirstlane(i);
            const int4 sa = *(const int4*)(srcoff + iu);
            const int4 sb = *(const int4*)(srcoff + iu + 4);
            const u32 h0 = *(const u32*)(hb + sa.x + lane4);
            const u32 h1 = *(const u32*)(hb + sa.y + lane4);
            const u32 h2 = *(const u32*)(hb + sa.z + lane4);
            const u32 h3 = *(const u32*)(hb + sa.w + lane4);
            const u32 h4 = *(const u32*)(hb + sb.x + lane4);
            const u32 h5 = *(const u32*)(hb + sb.y + lane4);
            const u32 h6 = *(const u32*)(hb + sb.z + lane4);
            const u32 h7 = *(const u32*)(hb + sb.w + lane4);
            acc0 += uif(h0 << 16); acc1 += uif(h0 & 0xFFFF0000u);
            acc0 += uif(h1 << 16); acc1 += uif(h1 & 0xFFFF0000u);
            acc0 += uif(h2 << 16); acc1 += uif(h2 & 0xFFFF0000u);
            acc0 += uif(h3 << 16); acc1 += uif(h3 & 0xFFFF0000u);
            acc0 += uif(h4 << 16); acc1 += uif(h4 & 0xFFFF0000u);
            acc0 += uif(h5 << 16); acc1 += uif(h5 & 0xFFFF0000u);
            acc0 += uif(h6 << 16); acc1 += uif(h6 & 0xFFFF0000u);
            acc0 += uif(h7 << 16); acc1 += uif(h7 & 0xFFFF0000u);
        }
        for (; i + 3 < end; i += 4) {
            const int iu = __builtin_amdgcn_readfirstlane(i);
            const int4 sa = *(const int4*)(srcoff + iu);
            const u32 h0 = *(const u32*)(hb + sa.x + lane4);
            const u32 h1 = *(const u32*)(hb + sa.y + lane4);
            const u32 h2 = *(const u32*)(hb + sa.z + lane4);
            const u32 h3 = *(const u32*)(hb + sa.w + lane4);
            acc0 += uif(h0 << 16); acc1 += uif(h0 & 0xFFFF0000u);
            acc0 += uif(h1 << 16); acc1 += uif(h1 & 0xFFFF0000u);
            acc0 += uif(h2 << 16); acc1 += uif(h2 & 0xFFFF0000u);
            acc0 += uif(h3 << 16); acc1 += uif(h3 & 0xFFFF0000u);
        }
        for (; i < end; ++i) {
            const int iu = __builtin_amdgcn_readfirstlane(i);
            const u32 h0 = *(const u32*)(hb + srcoff[iu] + lane4);
            acc0 += uif(h0 << 16); acc1 += uif(h0 & 0xFFFF0000u);
        }
        const u32 eg = eagg_l[(size_t)node*64 + lane];
        const u32 hn = *(const u32*)(hb + (size_t)node*256 + lane4);
        float t0 = fmaf(epsv, uif(hn << 16),          acc0 + uif(eg << 16));
        float t1 = fmaf(epsv, uif(hn & 0xFFFF0000u),  acc1 + uif(eg & 0xFFFF0000u));
        C16[(size_t)node*64 + lane] = pack_bf16(t0, t1);
    }
}

// ---------------------------------------------------------------------------
// bf16 MFMA GEMM (64 rows/block, R6 config), in-place safe.
// ---------------------------------------------------------------------------
__global__ __launch_bounds__(256) void conv_mfma_kernel(
    const unsigned short* X16, int M,
    const unsigned short* __restrict__ Wt,
    const float* __restrict__ scale, const float* __restrict__ off,
    const unsigned short* __restrict__ resid16,
    unsigned short* out16, int do_relu)
{
    __shared__ unsigned short Ws[128*128];
    for (int i = threadIdx.x*8; i < 128*128; i += 256*8) {
        int row = i >> 7;
        int bo = (i & 127) * 2;
        int4 v = *(const int4*)(Wt + i);
        *(int4*)((char*)Ws + row*256 + (bo ^ ((row & 7) << 4))) = v;
    }
    __syncthreads();
    const int wave = threadIdx.x >> 6, lane = threadIdx.x & 63;
    const int row0 = blockIdx.x*64 + wave*16;
    const int l15 = lane & 15, l4 = lane >> 4;
    int arow = row0 + l15; if (arow > M-1) arow = M-1;
    const unsigned short* ap = X16 + (size_t)arow*128 + l4*8;
    f32x4 acc[8];
    #pragma unroll
    for (int t = 0; t < 8; ++t) acc[t] = f32x4{0.f, 0.f, 0.f, 0.f};
    #pragma unroll
    for (int ks = 0; ks < 4; ++ks) {
        bf16x8 a = *(const bf16x8*)(ap + ks*32);
        #pragma unroll
        for (int t = 0; t < 8; ++t) {
            int brow = t*16 + l15;
            int bo = ks*64 + l4*16;
            bf16x8 b = *(const bf16x8*)((const char*)Ws + brow*256 + (bo ^ ((brow & 7) << 4)));
            acc[t] = __builtin_amdgcn_mfma_f32_16x16x32_bf16(a, b, acc[t], 0, 0, 0);
        }
    }
    #pragma unroll
    for (int t = 0; t < 8; ++t) {
        int col = t*16 + l15;
        float sc = scale[col], of = off[col];
        #pragma unroll
        for (int r = 0; r < 4; ++r) {
            int row = row0 + l4*4 + r;
            if (row < M) {
                float y = fmaf(acc[t][r], sc, of);
                if (do_relu) y = fmaxf(y, 0.f);
                if (resid16) y += uif((u32)resid16[(size_t)row*128 + col] << 16);
                out16[(size_t)row*128 + col] = bf16r(y);
            }
        }
    }
}

__global__ __launch_bounds__(256) void pool_kernel(
    const u32* __restrict__ h16, const int* __restrict__ goff,
    float* __restrict__ pooled)
{
    const int wave = threadIdx.x >> 6, lane = threadIdx.x & 63;
    const int g = blockIdx.x*4 + wave;
    if (g >= NGRAPH) return;
    float ax = 0.f, ay = 0.f;
    const int beg = goff[g], end = goff[g+1];
    for (int node = beg; node < end; ++node) {
        u32 v = h16[(size_t)node*64 + lane];
        ax += uif(v << 16); ay += uif(v & 0xFFFF0000u);
    }
    *(float2*)&pooled[g*128 + lane*2] = make_float2(ax, ay);
}

// fp32 vector GEMM for the small output MLP (512 rows)
__global__ __launch_bounds__(256) void gemm128_kernel(
    const float* __restrict__ in, int rows,
    const float* __restrict__ W,
    const float* __restrict__ scale, const float* __restrict__ off,
    float* out, int do_relu)
{
    __shared__ float Wsh[128*128];
    for (int i = threadIdx.x*4; i < 128*128; i += 256*4)
        *(float4*)&Wsh[i] = *(const float4*)&W[i];
    __syncthreads();
    const int wave = threadIdx.x >> 6, lane = threadIdx.x & 63;
    const int c0 = lane * 2;
    const float sc0 = scale ? scale[c0]   : 1.0f;
    const float sc1 = scale ? scale[c0+1] : 1.0f;
    const float of0 = off ? off[c0]   : 0.0f;
    const float of1 = off ? off[c0+1] : 0.0f;
    for (int rp = blockIdx.x*4 + wave; rp*2 < rows; rp += gridDim.x*4) {
        const int row0 = __builtin_amdgcn_readfirstlane(rp * 2);
        const float* xr = in + (size_t)row0 * 128;
        float a00 = 0.f, a01 = 0.f, a10 = 0.f, a11 = 0.f;
        #pragma unroll 8
        for (int k = 0; k < 128; ++k) {
            float x0 = xr[k];
            float x1 = xr[128 + k];
            float2 w = *(const float2*)&Wsh[k*128 + c0];
            a00 = fmaf(x0, w.x, a00); a01 = fmaf(x0, w.y, a01);
            a10 = fmaf(x1, w.x, a10); a11 = fmaf(x1, w.y, a11);
        }
        float y00 = fmaf(a00, sc0, of0), y01 = fmaf(a01, sc1, of1);
        float y10 = fmaf(a10, sc0, of0), y11 = fmaf(a11, sc1, of1);
        if (do_relu) {
            y00 = fmaxf(y00, 0.f); y01 = fmaxf(y01, 0.f);
            y10 = fmaxf(y10, 0.f); y11 = fmaxf(y11, 0.f);
        }
        *(float2*)&out[(size_t)row0*128 + c0]     = make_float2(y00, y01);
        *(float2*)&out[(size_t)(row0+1)*128 + c0] = make_float2(y10, y11);
    }
}

extern "C" void kernel_launch(void* const* d_in, const int* in_sizes, int n_in,
                              void* d_out, int out_size, void* d_ws, size_t ws_size,
                              hipStream_t stream)
{
    const float* x         = (const float*)d_in[0];
    const int*   eidx      = (const int*)d_in[1];
    const float* eattr     = (const float*)d_in[2];
    const int*   batch     = (const int*)d_in[3];
    const float* in_W      = (const float*)d_in[4];
    const float* in_b      = (const float*)d_in[5];
    const float* in_g      = (const float*)d_in[6];
    const float* in_beta   = (const float*)d_in[7];
    const float* edge_W    = (const float*)d_in[8];
    const float* edge_b    = (const float*)d_in[9];
    const float* edge_g    = (const float*)d_in[10];
    const float* edge_beta = (const float*)d_in[11];
    const float* conv_W    = (const float*)d_in[12];
    const float* epsp      = (const float*)d_in[13];
    const float* bn_g      = (const float*)d_in[14];
    const float* bn_b      = (const float*)d_in[15];
    const float* out_W1    = (const float*)d_in[16];
    const float* out_b1    = (const float*)d_in[17];
    const float* out_g1    = (const float*)d_in[18];
    const float* out_beta1 = (const float*)d_in[19];
    const float* out_W2    = (const float*)d_in[20];
    const float* out_b2    = (const float*)d_in[21];

    const int N = in_sizes[0] / 128;
    const int E = in_sizes[1] / 2;
    const int* src = eidx;
    const int* dst = eidx + E;

    char* ws = (char*)d_ws;
    size_t o = 0;
    auto alloc = [&](size_t bytes) { void* p = ws + o; o = (o + bytes + 255) & ~(size_t)255; return p; };
    unsigned short* P    = (unsigned short*)alloc((size_t)N * 128 * 2);
    unsigned short* Q    = (unsigned short*)alloc((size_t)N * 128 * 2);
    char*  rec           = (char*)alloc((size_t)E * RSTRIDE);
    int*   srcoff        = (int*)alloc((size_t)E * 4);
    u32*   eagg          = (u32*)alloc((size_t)N * 64 * 2 * 4);  // 2 planes bf16x2
    int*   offs          = (int*)alloc((size_t)(N + 1) * 4);
    int*   cursor        = (int*)alloc((size_t)N * 4);
    int*   cnt           = (int*)alloc((size_t)N * 4);
    int*   goff          = (int*)alloc((NGRAPH + 1) * 4);
    float* pooled        = (float*)alloc(NGRAPH * 128 * 4);
    float* o1            = (float*)alloc(NGRAPH * 128 * 4);
    float* consts        = (float*)alloc(2560 * 4);
    _Float16* wfrag      = (_Float16*)alloc(4 * 8 * 64 * 8 * 2);
    unsigned short* WtAll = (unsigned short*)alloc(5 * 128 * 128 * 2);

    prep_kernel<<<1, 256, 0, stream>>>(in_b, in_g, in_beta,
                                       edge_b, edge_g, edge_beta,
                                       bn_g, bn_b, out_b1, out_g1, out_beta1,
                                       consts);
    wfrag_kernel<<<64, 256, 0, stream>>>(edge_W, edge_g, wfrag);
    prepw_kernel<<<80, 256, 0, stream>>>(in_W, conv_W, WtAll);
    xconv_kernel<<<2048, 256, 0, stream>>>(x, (u32*)Q, N * 32);

    (void)hipMemsetAsync(cnt, 0, (size_t)N * 4, stream);
    count_kernel<<<2048, 256, 0, stream>>>(dst, E, cnt);
    scan_kernel<<<1, 1024, 0, stream>>>(cnt, N, E, offs, cursor);
    scatter_kernel<<<2048, 256, 0, stream>>>(src, dst, eattr, E, cursor, rec);
    extract_srcoff_kernel<<<2048, 256, 0, stream>>>(rec, E, srcoff);
    goff_kernel<<<3, 256, 0, stream>>>(batch, N, goff);

    const int gblocks = (N + 63) / 64;
    // input encoder, in-place on Q: h0 = bf16(relu(bn(x@in_W)))
    conv_mfma_kernel<<<gblocks, 256, 0, stream>>>(Q, N, WtAll,
                                                  consts, consts + 128,
                                                  nullptr, Q, 1);

    unsigned short* cur = Q;
    unsigned short* oth = P;
    for (int l = 0; l < 4; ++l) {
        if ((l & 1) == 0)  // 2-plane buffer: recompute per layer pair
            eagg2_kernel<<<2048, 256, 0, stream>>>(rec, offs, wfrag, consts,
                                                   l, eagg, N);
        hagg_kernel<<<2048, 256, 0, stream>>>((const char*)cur, srcoff, offs,
                                              eagg + (size_t)(l & 1) * N * 64,
                                              epsp, l, (u32*)oth, N);
        conv_mfma_kernel<<<gblocks, 256, 0, stream>>>(oth, N,
                                                      WtAll + (size_t)(1 + l)*16384,
                                                      consts + 1280 + l*128,
                                                      consts + 1792 + l*128,
                                                      cur, oth, 1);
        unsigned short* t = cur; cur = oth; oth = t;
    }

    pool_kernel<<<128, 256, 0, stream>>>((const u32*)cur, goff, pooled);

    gemm128_kernel<<<64, 256, 0, stream>>>(pooled, NGRAPH, out_W1,
                                           consts + 2304, consts + 2432, o1, 1);
    gemm128_kernel<<<64, 256, 0, stream>>>(o1, NGRAPH, out_W2,
                                           nullptr, out_b2, (float*)d_out, 0);
}